// Round 5
// baseline (6371.498 us; speedup 1.0000x reference)
//
#include <hip/hip_runtime.h>
#include <hip/hip_bf16.h>
#include <hip/hip_cooperative_groups.h>
#include <cstddef>

namespace cg = cooperative_groups;

#define NN 1024
#define BB 2
#define TT 12

typedef __attribute__((ext_vector_type(8))) short short8;
typedef __attribute__((ext_vector_type(4))) float f32x4;

__device__ __forceinline__ float sigmoidf_(float v) { return 1.0f / (1.0f + expf(-v)); }

struct GParams {
    const float* x; const int* mask; const float* adj;
    const float *Wr, *br, *Wu, *bu, *Wc, *bc, *Wfs, *bfs, *Wdin, *bdin;
    const float *Wgc, *bgc, *Wlout, *blout, *Wro, *bro, *pa;
    float *h, *gcp, *outb, *x1b, *zc, *ub, *Wcomb, *bcomb, *blout2;
    __hip_bfloat16 *adjb, *yb, *zb, *zcb;
    float *imp, *pred, *repr;
};

// ---------------- init: h=0, weight folds, adj->bf16 ----------------
__device__ void ph_init(const GParams& P)
{
    const int tid0 = blockIdx.x * 512 + threadIdx.x;   // 0..131071
    if (tid0 < 131072) P.h[tid0] = 0.f;
    if (tid0 < 8448) {
        const int o = tid0 / 66, k = tid0 % 66;
        const float* g = P.Wgc + (size_t)(o & 63) * 128 + (o >> 6) * 64;
        float a = 0.f;
#pragma unroll 8
        for (int c = 0; c < 64; ++c) a += g[c] * P.Wdin[c * 66 + k];
        P.Wcomb[tid0] = a;
    } else if (tid0 < 8576) {
        const int o = tid0 - 8448;
        const float* g = P.Wgc + (size_t)(o & 63) * 128 + (o >> 6) * 64;
        float a = 0.f;
#pragma unroll 8
        for (int c = 0; c < 64; ++c) a += g[c] * P.bdin[c];
        P.bcomb[o] = a;
    } else if (tid0 < 8640) {
        const int oc = tid0 - 8576;
        float a = P.blout[oc];
#pragma unroll 8
        for (int j = 0; j < 64; ++j) a += P.Wlout[(size_t)oc * 128 + j] * P.bgc[j];
        P.blout2[oc] = a;
    }
    for (int i = tid0; i < 1048576; i += 131072) {
        float4 v = reinterpret_cast<const float4*>(P.adj)[i];
        const size_t e = (size_t)i * 4;
        P.adjb[e + 0] = __float2bfloat16(v.x);
        P.adjb[e + 1] = __float2bfloat16(v.y);
        P.adjb[e + 2] = __float2bfloat16(v.z);
        P.adjb[e + 3] = __float2bfloat16(v.w);
    }
}

// ---------------- split-K (8-wave) MFMA diffusion ----------------
// dst[c][w] = sum_v src[c][v] * adj[sb][w][v]; 256 blocks = 64 n-tiles x 4 sb
template<int C>
__device__ void ph_dif(const GParams& P,
    const __hip_bfloat16* __restrict__ srcb, int srcCT, int srcOff, int srcStep,
    float* __restrict__ dstf, int dfCT, int dfOff, int dfStep,
    __hip_bfloat16* __restrict__ dstb, int dbCT, int dbOff, int dbStep,
    f32x4* red)
{
    constexpr int MT = (C + 15) / 16;
    const int blk = blockIdx.x;
    const int sb = blk >> 6, s = sb >> 1, b = sb & 1;
    const int n0 = (blk & 63) * 16;
    const int wave = threadIdx.x >> 6, lane = threadIdx.x & 63;
    const int lr = lane & 15, lq = lane >> 4;

    const __hip_bfloat16* A = P.adjb + ((size_t)sb << 20) + (size_t)(n0 + lr) * NN + lq * 8;
    const __hip_bfloat16* X = srcb + ((size_t)(b * srcCT + srcOff + s * srcStep + lr)) * NN + lq * 8;

    f32x4 acc[MT];
#pragma unroll
    for (int m = 0; m < MT; ++m) acc[m] = (f32x4){0.f, 0.f, 0.f, 0.f};

    const short8 zsh = {0, 0, 0, 0, 0, 0, 0, 0};
    const int vbeg = wave * 128;
#pragma unroll
    for (int i = 0; i < 4; ++i) {
        const int v0 = vbeg + i * 32;
        short8 bfr = *reinterpret_cast<const short8*>(A + v0);
        short8 af[MT];
#pragma unroll
        for (int m = 0; m < MT; ++m) {
            short8 tv = *reinterpret_cast<const short8*>(X + (size_t)m * 16 * NN + v0);
            if ((C & 15) != 0 && m == MT - 1 && lr >= (C & 15)) tv = zsh;
            af[m] = tv;
        }
#pragma unroll
        for (int m = 0; m < MT; ++m)
            acc[m] = __builtin_amdgcn_mfma_f32_16x16x32_bf16(af[m], bfr, acc[m], 0, 0, 0);
    }

    if (wave > 0) {
#pragma unroll
        for (int m = 0; m < MT; ++m) red[((wave - 1) * MT + m) * 64 + lane] = acc[m];
    }
    __syncthreads();
    if (wave == 0) {
#pragma unroll
        for (int m = 0; m < MT; ++m)
#pragma unroll
            for (int w = 0; w < 7; ++w) acc[m] += red[(w * MT + m) * 64 + lane];

        const size_t dbF = (size_t)(b * dfCT + dfOff + s * dfStep);
        const size_t dbB = dstb ? (size_t)(b * dbCT + dbOff + s * dbStep) : 0;
#pragma unroll
        for (int m = 0; m < MT; ++m) {
#pragma unroll
            for (int q = 0; q < 4; ++q) {
                const int c = m * 16 + lq * 4 + q;
                if (c < C) {
                    const float val = acc[m][q];
                    if (dstf) dstf[(dbF + c) * NN + n0 + lr] = val;
                    if (dstb) dstb[(dbB + c) * NN + n0 + lr] = __float2bfloat16(val);
                }
            }
        }
    }
    __syncthreads();
}

// ---------------- prestep: xs1, x1, y = Wcomb.[x1,m,h]+bcomb ----------------
__device__ void ph_prestep(const GParams& P, int t)
{
#pragma unroll
    for (int it = 0; it < 2; ++it) {
        const int unit = blockIdx.x * 2 + (threadIdx.x >> 8) + it * 512;  // 0..1023
        const int tl = threadIdx.x & 255;
        const int p = (unit & 7) * 256 + tl;
        const int o = unit >> 3;
        const int b = p >> 10, n = p & (NN - 1);
        const float* hB = P.h + (size_t)b * 64 * NN + n;
        const float* w = P.Wcomb + (size_t)o * 66;
        float a = 0.f, xs1 = 0.f;
#pragma unroll 8
        for (int j = 0; j < 64; ++j) {
            float hv = hB[(size_t)j * NN];
            xs1 += P.Wfs[j] * hv;
            a += w[2 + j] * hv;
        }
        xs1 += P.bfs[0];
        const size_t xi = (size_t)(b * NN + n) * TT + t;
        const int mi = P.mask[xi];
        const float mf = (float)mi;
        const float x1 = mi ? P.x[xi] : xs1;
        a += w[0] * x1 + w[1] * mf + P.bcomb[o];
        P.yb[(size_t)(b * 128 + o) * NN + n] = __float2bfloat16(a);
        if (o == 0) { P.pred[xi] = xs1; P.x1b[p] = x1; }
    }
}

// ---------------- dec2: lo = prelu(Wlout.[gc0+gc1,h]+blout2) ----------------
__device__ void ph_dec2(const GParams& P, int t)
{
    const int unit = blockIdx.x * 2 + (threadIdx.x >> 8);  // 0..511
    const int tl = threadIdx.x & 255;
    const int p = (unit & 7) * 256 + tl;
    const int oc = unit >> 3;
    const int b = p >> 10, n = p & (NN - 1);
    const float* gB = P.gcp + (size_t)b * 128 * NN + n;
    const float* hB = P.h + (size_t)b * 64 * NN + n;
    const float* w = P.Wlout + (size_t)oc * 128;
    float a = 0.f;
#pragma unroll 8
    for (int j = 0; j < 64; ++j) {
        float gv = gB[(size_t)j * NN] + gB[(size_t)(64 + j) * NN];
        a += w[j] * gv;
        a += w[64 + j] * hB[(size_t)j * NN];
    }
    float v = a + P.blout2[oc];
    v = (v >= 0.f) ? v : P.pa[0] * v;
    P.outb[(size_t)(b * 64 + oc) * NN + n] = v;
    P.repr[(((size_t)b * 128 + oc) * NN + n) * TT + t] = v;
    const float hv = hB[(size_t)oc * NN];
    P.repr[(((size_t)b * 128 + 64 + oc) * NN + n) * TT + t] = hv;
    P.zb[((size_t)b * 330 + 2 + oc) * NN + n] = __float2bfloat16(hv);
}

// ---------------- xs2: wave reduce; imp; zb ch0,1 ----------------
__device__ void ph_xs2(const GParams& P, int t)
{
    const int unit = blockIdx.x * 2 + (threadIdx.x >> 8);  // 0..511
    const int tl = threadIdx.x & 255;
    const int nl = tl >> 6, lane = tl & 63;
    const int p = unit * 4 + nl;
    const int b = p >> 10, n = p & (NN - 1);
    float v = P.Wro[lane] * P.outb[(size_t)(b * 64 + lane) * NN + n]
            + P.Wro[64 + lane] * P.h[(size_t)(b * 64 + lane) * NN + n];
#pragma unroll
    for (int off = 32; off > 0; off >>= 1) v += __shfl_xor(v, off);
    if (lane == 0) {
        const float xs2 = v + P.bro[0];
        const size_t xi = (size_t)(b * NN + n) * TT + t;
        P.imp[xi] = xs2;
        const int mi = P.mask[xi];
        const float x2 = mi ? P.x1b[p] : xs2;
        P.zb[(size_t)b * 330 * NN + n] = __float2bfloat16(x2);
        P.zb[((size_t)b * 330 + 1) * NN + n] = __float2bfloat16((float)mi);
    }
}

// ---------------- gates: r,u; zc ch2..65 = r*h ----------------
__device__ void ph_gates(const GParams& P)
{
    const int unit = blockIdx.x * 2 + (threadIdx.x >> 8);
    const int tl = threadIdx.x & 255;
    const int p = (unit & 7) * 256 + tl;
    const int oc = unit >> 3;
    const int b = p >> 10, n = p & (NN - 1);
    const __hip_bfloat16* zB = P.zb + (size_t)b * 330 * NN + n;
    const float* wr = P.Wr + (size_t)oc * 330;
    const float* wu = P.Wu + (size_t)oc * 330;
    float r = 0.f, u = 0.f;
#pragma unroll 10
    for (int j = 0; j < 330; ++j) {
        float zv = __bfloat162float(zB[(size_t)j * NN]);
        r += wr[j] * zv; u += wu[j] * zv;
    }
    r = sigmoidf_(r + P.br[oc]);
    u = sigmoidf_(u + P.bu[oc]);
    const size_t hidx = (size_t)(b * 64 + oc) * NN + n;
    P.ub[hidx] = u;
    const float rh = r * P.h[hidx];
    P.zc[((size_t)b * 330 + 2 + oc) * NN + n] = rh;
    P.zcb[((size_t)b * 330 + 2 + oc) * NN + n] = __float2bfloat16(rh);
    if (oc == 0) {
        const __hip_bfloat16 z0 = zB[0], z1 = zB[NN];
        P.zc[(size_t)b * 330 * NN + n] = __bfloat162float(z0);
        P.zc[((size_t)b * 330 + 1) * NN + n] = __bfloat162float(z1);
        P.zcb[(size_t)b * 330 * NN + n] = z0;
        P.zcb[((size_t)b * 330 + 1) * NN + n] = z1;
    }
}

// ---------------- cell: c = tanh(Wc.zc+bc); h update ----------------
__device__ void ph_cell(const GParams& P)
{
    const int unit = blockIdx.x * 2 + (threadIdx.x >> 8);
    const int tl = threadIdx.x & 255;
    const int p = (unit & 7) * 256 + tl;
    const int oc = unit >> 3;
    const int b = p >> 10, n = p & (NN - 1);
    const float* zB = P.zc + (size_t)b * 330 * NN + n;
    const float* w = P.Wc + (size_t)oc * 330;
    float a = 0.f;
#pragma unroll 10
    for (int j = 0; j < 330; ++j) a += w[j] * zB[(size_t)j * NN];
    const float c = tanhf(a + P.bc[oc]);
    const size_t idx = (size_t)(b * 64 + oc) * NN + n;
    const float u = P.ub[idx];
    P.h[idx] = u * P.h[idx] + (1.f - u) * c;
}

// ---------------- mega kernel ----------------
__global__ __launch_bounds__(512) void k_mega(GParams P)
{
    cg::grid_group gg = cg::this_grid();
    __shared__ f32x4 red[7 * 5 * 64];

    ph_init(P);
    gg.sync();

    for (int t = 0; t < TT; ++t) {
        ph_prestep(P, t);                                               gg.sync();
        ph_dif<64>(P, P.yb, 128, 0, 64, P.gcp, 128, 0, 64,
                   (__hip_bfloat16*)nullptr, 0, 0, 0, red);             gg.sync();
        ph_dec2(P, t);                                                  gg.sync();
        ph_xs2(P, t);                                                   gg.sync();
        ph_dif<66>(P, P.zb, 330, 0, 0, (float*)nullptr, 0, 0, 0,
                   P.zb, 330, 66, 132, red);                            gg.sync();
        ph_dif<66>(P, P.zb, 330, 66, 132, (float*)nullptr, 0, 0, 0,
                   P.zb, 330, 132, 132, red);                           gg.sync();
        ph_gates(P);                                                    gg.sync();
        ph_dif<66>(P, P.zcb, 330, 0, 0, P.zc, 330, 66, 132,
                   P.zcb, 330, 66, 132, red);                           gg.sync();
        ph_dif<66>(P, P.zcb, 330, 66, 132, P.zc, 330, 132, 132,
                   (__hip_bfloat16*)nullptr, 0, 0, 0, red);             gg.sync();
        ph_cell(P);                                                     gg.sync();
    }
}

extern "C" void kernel_launch(void* const* d_in, const int* in_sizes, int n_in,
                              void* d_out, int out_size, void* d_ws, size_t ws_size,
                              hipStream_t stream)
{
    GParams P;
    P.x     = (const float*)d_in[0];
    P.mask  = (const int*)  d_in[1];
    P.adj   = (const float*)d_in[2];
    P.Wr    = (const float*)d_in[3];
    P.br    = (const float*)d_in[4];
    P.Wu    = (const float*)d_in[5];
    P.bu    = (const float*)d_in[6];
    P.Wc    = (const float*)d_in[7];
    P.bc    = (const float*)d_in[8];
    P.Wfs   = (const float*)d_in[9];
    P.bfs   = (const float*)d_in[10];
    P.Wdin  = (const float*)d_in[11];
    P.bdin  = (const float*)d_in[12];
    P.Wgc   = (const float*)d_in[13];
    P.bgc   = (const float*)d_in[14];
    P.Wlout = (const float*)d_in[15];
    P.blout = (const float*)d_in[16];
    P.Wro   = (const float*)d_in[17];
    P.bro   = (const float*)d_in[18];
    P.pa    = (const float*)d_in[19];

    float* ws = (float*)d_ws;
    P.h      = ws;                 // 131072
    P.gcp    = ws + 131072;        // 262144
    P.outb   = ws + 393216;        // 131072
    P.x1b    = ws + 524288;        // 2048
    P.zc     = ws + 526336;        // 675840
    P.ub     = ws + 1202176;       // 131072
    P.Wcomb  = ws + 1333248;       // 8448
    P.bcomb  = ws + 1341696;       // 128
    P.blout2 = ws + 1341824;       // 64 -> fp32 end 1341888
    __hip_bfloat16* bfp = (__hip_bfloat16*)(ws + 1341888);
    P.adjb = bfp;                  // 4194304
    P.yb   = bfp + 4194304;        // 262144
    P.zb   = bfp + 4456448;        // 675840
    P.zcb  = bfp + 5132288;        // 675840 (bf16 end 5808128)

    P.imp  = (float*)d_out;
    P.pred = P.imp + (size_t)BB * NN * TT;
    P.repr = P.imp + (size_t)2 * BB * NN * TT;

    void* kargs[] = { &P };
    hipLaunchCooperativeKernel((const void*)k_mega, dim3(256), dim3(512),
                               kargs, 0, stream);
}

// Round 6
// 1071.892 us; speedup vs baseline: 5.9442x; 5.9442x over previous
//
#include <hip/hip_runtime.h>
#include <hip/hip_bf16.h>
#include <cstddef>

#define NN 1024
#define BB 2
#define TT 12

typedef __attribute__((ext_vector_type(8))) short short8;
typedef __attribute__((ext_vector_type(4))) float f32x4;

__device__ __forceinline__ float sigmoidf_(float v) { return 1.0f / (1.0f + expf(-v)); }

// ---------------- adj fp32 -> bf16 ----------------
__global__ __launch_bounds__(256) void k_cvt(const float* __restrict__ a,
                                             __hip_bfloat16* __restrict__ ab)
{
    size_t i = ((size_t)blockIdx.x * 256 + threadIdx.x) * 4;
    float4 v = *reinterpret_cast<const float4*>(a + i);
    ab[i + 0] = __float2bfloat16(v.x);
    ab[i + 1] = __float2bfloat16(v.y);
    ab[i + 2] = __float2bfloat16(v.z);
    ab[i + 3] = __float2bfloat16(v.w);
}

// ---------------- one-time weight folds ----------------
__global__ __launch_bounds__(256) void k_prep(
    const float* __restrict__ Wgc, const float* __restrict__ bgc,
    const float* __restrict__ Wdin, const float* __restrict__ bdin,
    const float* __restrict__ Wlout, const float* __restrict__ blout,
    float* __restrict__ Wcomb, float* __restrict__ bcomb, float* __restrict__ blout2)
{
    const int idx = blockIdx.x * 256 + threadIdx.x;
    if (idx < 128 * 66) {
        const int o = idx / 66, k = idx % 66;
        const float* g = Wgc + (size_t)(o & 63) * 128 + (o >> 6) * 64;
        float a = 0.f;
#pragma unroll 8
        for (int c = 0; c < 64; ++c) a += g[c] * Wdin[c * 66 + k];
        Wcomb[idx] = a;
    } else if (idx < 8448 + 128) {
        const int o = idx - 8448;
        const float* g = Wgc + (size_t)(o & 63) * 128 + (o >> 6) * 64;
        float a = 0.f;
#pragma unroll 8
        for (int c = 0; c < 64; ++c) a += g[c] * bdin[c];
        bcomb[o] = a;
    } else if (idx < 8448 + 128 + 64) {
        const int oc = idx - 8576;
        float a = blout[oc];
#pragma unroll 8
        for (int j = 0; j < 64; ++j) a += Wlout[(size_t)oc * 128 + j] * bgc[j];
        blout2[oc] = a;
    }
}

// ---------------- one-time A^2 (bf16 MFMA, LDS-transposed B) ----------------
// adj2b[sb][w][v] = sum_k adjb[sb][w][k] * adjb[sb][k][v]
// grid (64 v-tiles, 4 sb, 16 w-chunks); block 256 = 4 waves, wave = one 16-row m-tile
__global__ __launch_bounds__(256) void k_a2(const __hip_bfloat16* __restrict__ adjb,
                                            __hip_bfloat16* __restrict__ adj2b)
{
    const int sb = blockIdx.y;
    const int v0 = blockIdx.x * 16;
    const int w0 = blockIdx.z * 64;
    const int wv = threadIdx.x >> 6, lane = threadIdx.x & 63;
    const int lr = lane & 15, lq = lane >> 4;
    const __hip_bfloat16* A = adjb + ((size_t)sb << 20);

    __shared__ __align__(16) short bt[16][1032];   // [v][k], pad for banks/alignment
    for (int idx = threadIdx.x; idx < 16 * 1024; idx += 256) {
        const int k = idx >> 4, j = idx & 15;
        bt[j][k] = *reinterpret_cast<const short*>(A + (size_t)k * NN + v0 + j);
    }
    __syncthreads();

    const __hip_bfloat16* Arow = A + (size_t)(w0 + wv * 16 + lr) * NN;
    f32x4 acc = (f32x4){0.f, 0.f, 0.f, 0.f};
#pragma unroll 4
    for (int k0 = 0; k0 < NN; k0 += 32) {
        short8 bf = *reinterpret_cast<const short8*>(&bt[lr][k0 + lq * 8]);
        short8 af = *reinterpret_cast<const short8*>(Arow + k0 + lq * 8);
        acc = __builtin_amdgcn_mfma_f32_16x16x32_bf16(af, bf, acc, 0, 0, 0);
    }
    __hip_bfloat16* D = adj2b + ((size_t)sb << 20);
#pragma unroll
    for (int q = 0; q < 4; ++q) {
        const int w = w0 + wv * 16 + lq * 4 + q;
        D[(size_t)w * NN + v0 + lr] = __float2bfloat16(acc[q]);
    }
}

// ---------------- MFMA diffusion (order-1 and order-2 in one launch) ----------------
// combo = blockIdx.y: ord = combo>>2 (0: mat0, 1: mat1), sb = combo&3
// dst[b, Off + s*Step + ord*OrdStep + c][w] = sum_v src[b, srcOff + c][v] * mat[sb][w][v]
template<int C>
__global__ __launch_bounds__(256) void k_dif(
    const __hip_bfloat16* __restrict__ mat0, const __hip_bfloat16* __restrict__ mat1,
    const __hip_bfloat16* __restrict__ srcb, int srcCT, int srcOff, int srcStep,
    float* __restrict__ dstf, int dfCT, int dfOff, int dfStep, int dfOrd,
    __hip_bfloat16* __restrict__ dstb, int dbCT, int dbOff, int dbStep, int dbOrd)
{
    constexpr int MT = (C + 15) / 16;
    const int combo = blockIdx.y;
    const int ord = combo >> 2, sb = combo & 3;
    const int s = sb >> 1, b = sb & 1;
    const int wave = threadIdx.x >> 6, lane = threadIdx.x & 63;
    const int lr = lane & 15, lq = lane >> 4;
    const int n0 = blockIdx.x * 16;

    const __hip_bfloat16* M = (ord ? mat1 : mat0) + ((size_t)sb << 20);
    const __hip_bfloat16* A = M + (size_t)(n0 + lr) * NN + lq * 8;
    const __hip_bfloat16* X = srcb + ((size_t)(b * srcCT + srcOff + s * srcStep + lr)) * NN + lq * 8;

    f32x4 acc[MT];
#pragma unroll
    for (int m = 0; m < MT; ++m) acc[m] = (f32x4){0.f, 0.f, 0.f, 0.f};

    const short8 zsh = {0, 0, 0, 0, 0, 0, 0, 0};
    const int vbeg = wave * 256;
#pragma unroll 4
    for (int i = 0; i < 8; ++i) {
        const int v0 = vbeg + i * 32;
        short8 bfr = *reinterpret_cast<const short8*>(A + v0);
        short8 af[MT];
#pragma unroll
        for (int m = 0; m < MT; ++m) {
            short8 tv = *reinterpret_cast<const short8*>(X + (size_t)m * 16 * NN + v0);
            if ((C & 15) != 0 && m == MT - 1 && lr >= (C & 15)) tv = zsh;
            af[m] = tv;
        }
#pragma unroll
        for (int m = 0; m < MT; ++m)
            acc[m] = __builtin_amdgcn_mfma_f32_16x16x32_bf16(af[m], bfr, acc[m], 0, 0, 0);
    }

    __shared__ f32x4 red[3][MT][64];
    if (wave > 0) {
#pragma unroll
        for (int m = 0; m < MT; ++m) red[wave - 1][m][lane] = acc[m];
    }
    __syncthreads();
    if (wave == 0) {
#pragma unroll
        for (int m = 0; m < MT; ++m)
            acc[m] += red[0][m][lane] + red[1][m][lane] + red[2][m][lane];

        const size_t dbF = (size_t)(b * dfCT + dfOff + s * dfStep + ord * dfOrd);
        const size_t dbB = (size_t)(b * dbCT + dbOff + s * dbStep + ord * dbOrd);
#pragma unroll
        for (int m = 0; m < MT; ++m) {
#pragma unroll
            for (int q = 0; q < 4; ++q) {
                const int c = m * 16 + lq * 4 + q;
                if (c < C) {
                    const float val = acc[m][q];
                    if (dstf) dstf[(dbF + c) * NN + n0 + lr] = val;
                    if (dstb) dstb[(dbB + c) * NN + n0 + lr] = __float2bfloat16(val);
                }
            }
        }
    }
}

// ---------------- prestep: xs1, x1, y = Wcomb.[x1,m,h]+bcomb ----------------
__global__ __launch_bounds__(256) void k_prestep(
    const float* __restrict__ x, const int* __restrict__ mask, const float* __restrict__ h,
    const float* __restrict__ Wfs, const float* __restrict__ bfs,
    const float* __restrict__ Wcomb, const float* __restrict__ bcomb,
    __hip_bfloat16* __restrict__ yb, float* __restrict__ x1buf, float* __restrict__ pred, int t)
{
    const int p = blockIdx.x * 256 + threadIdx.x;
    const int b = p >> 10, n = p & (NN - 1);
    const int o = blockIdx.y;
    const float* hB = h + (size_t)b * 64 * NN + n;
    const float* w = Wcomb + (size_t)o * 66;
    float a = 0.f, xs1 = 0.f;
#pragma unroll 8
    for (int j = 0; j < 64; ++j) {
        float hv = hB[(size_t)j * NN];
        xs1 += Wfs[j] * hv;
        a += w[2 + j] * hv;
    }
    xs1 += bfs[0];
    const size_t xi = (size_t)(b * NN + n) * TT + t;
    const int mi = mask[xi];
    const float mf = (float)mi;
    const float x1 = mi ? x[xi] : xs1;
    a += w[0] * x1 + w[1] * mf + bcomb[o];
    yb[(size_t)(b * 128 + o) * NN + n] = __float2bfloat16(a);
    if (blockIdx.y == 0) { pred[xi] = xs1; x1buf[p] = x1; }
}

// ---------------- stepB: dec2 + xs2 fused (wave-per-node, lane = channel) ----------------
__global__ __launch_bounds__(256) void k_stepB(
    const float* __restrict__ gcp, const float* __restrict__ h,
    const float* __restrict__ Wlout, const float* __restrict__ blout2,
    const float* __restrict__ prelu_a, const float* __restrict__ Wro,
    const float* __restrict__ bro, const float* __restrict__ x1b,
    const float* __restrict__ x, const int* __restrict__ mask,
    float* __restrict__ imp, float* __restrict__ repr, __hip_bfloat16* __restrict__ zb, int t)
{
    const int wv = threadIdx.x >> 6, lane = threadIdx.x & 63;
    const int p = blockIdx.x * 4 + wv;          // node 0..2047
    const int b = p >> 10, n = p & (NN - 1);
    __shared__ float gl[4][64], hl[4][64];
    const float g0 = gcp[(size_t)(b * 128 + lane) * NN + n];
    const float g1 = gcp[(size_t)(b * 128 + 64 + lane) * NN + n];
    const float hv = h[(size_t)(b * 64 + lane) * NN + n];
    gl[wv][lane] = g0 + g1;
    hl[wv][lane] = hv;
    __syncthreads();
    const float* w = Wlout + (size_t)lane * 128;
    float a = 0.f;
#pragma unroll 8
    for (int j = 0; j < 64; ++j)
        a += w[j] * gl[wv][j] + w[64 + j] * hl[wv][j];
    float v = a + blout2[lane];
    v = (v >= 0.f) ? v : prelu_a[0] * v;
    repr[(((size_t)b * 128 + lane) * NN + n) * TT + t] = v;
    repr[(((size_t)b * 128 + 64 + lane) * NN + n) * TT + t] = hv;
    zb[((size_t)b * 330 + 2 + lane) * NN + n] = __float2bfloat16(hv);
    float s = Wro[lane] * v + Wro[64 + lane] * hv;
#pragma unroll
    for (int off = 32; off > 0; off >>= 1) s += __shfl_xor(s, off);
    if (lane == 0) {
        const float xs2 = s + bro[0];
        const size_t xi = (size_t)(b * NN + n) * TT + t;
        imp[xi] = xs2;
        const int mi = mask[xi];
        const float x2 = mi ? x1b[p] : xs2;
        zb[(size_t)b * 330 * NN + n] = __float2bfloat16(x2);
        zb[((size_t)b * 330 + 1) * NN + n] = __float2bfloat16((float)mi);
    }
}

// ---------------- gates: r,u; zc/zcb ch0..65 ----------------
__global__ __launch_bounds__(256) void k_gates(
    const __hip_bfloat16* __restrict__ zb, const float* __restrict__ h,
    const float* __restrict__ Wr, const float* __restrict__ br,
    const float* __restrict__ Wu, const float* __restrict__ bu,
    float* __restrict__ ubuf, float* __restrict__ zc, __hip_bfloat16* __restrict__ zcb)
{
    const int p = blockIdx.x * 256 + threadIdx.x;
    const int b = p >> 10, n = p & (NN - 1);
    const int oc = blockIdx.y;
    const __hip_bfloat16* zB = zb + (size_t)b * 330 * NN + n;
    const float* wr = Wr + (size_t)oc * 330;
    const float* wu = Wu + (size_t)oc * 330;
    float r = 0.f, u = 0.f;
#pragma unroll 10
    for (int j = 0; j < 330; ++j) {
        float zv = __bfloat162float(zB[(size_t)j * NN]);
        r += wr[j] * zv; u += wu[j] * zv;
    }
    r = sigmoidf_(r + br[oc]);
    u = sigmoidf_(u + bu[oc]);
    const size_t hidx = (size_t)(b * 64 + oc) * NN + n;
    ubuf[hidx] = u;
    const float rh = r * h[hidx];
    zc[((size_t)b * 330 + 2 + oc) * NN + n] = rh;
    zcb[((size_t)b * 66 + 2 + oc) * NN + n] = __float2bfloat16(rh);
    if (blockIdx.y == 0) {
        const __hip_bfloat16 z0 = zB[0], z1 = zB[NN];
        zc[(size_t)b * 330 * NN + n] = __bfloat162float(z0);
        zc[((size_t)b * 330 + 1) * NN + n] = __bfloat162float(z1);
        zcb[(size_t)b * 66 * NN + n] = z0;
        zcb[((size_t)b * 66 + 1) * NN + n] = z1;
    }
}

// ---------------- cell: c = tanh(Wc.zc+bc); h update ----------------
__global__ __launch_bounds__(256) void k_cell(
    const float* __restrict__ zc, const float* __restrict__ ubuf,
    const float* __restrict__ Wc, const float* __restrict__ bc,
    float* __restrict__ h)
{
    const int p = blockIdx.x * 256 + threadIdx.x;
    const int b = p >> 10, n = p & (NN - 1);
    const int oc = blockIdx.y;
    const float* zB = zc + (size_t)b * 330 * NN + n;
    const float* w = Wc + (size_t)oc * 330;
    float a = 0.f;
#pragma unroll 10
    for (int j = 0; j < 330; ++j) a += w[j] * zB[(size_t)j * NN];
    const float c = tanhf(a + bc[oc]);
    const size_t idx = (size_t)(b * 64 + oc) * NN + n;
    const float u = ubuf[idx];
    h[idx] = u * h[idx] + (1.f - u) * c;
}

extern "C" void kernel_launch(void* const* d_in, const int* in_sizes, int n_in,
                              void* d_out, int out_size, void* d_ws, size_t ws_size,
                              hipStream_t stream)
{
    const float* x     = (const float*)d_in[0];
    const int*   mask  = (const int*)  d_in[1];
    const float* adj   = (const float*)d_in[2];
    const float* Wr    = (const float*)d_in[3];
    const float* br    = (const float*)d_in[4];
    const float* Wu    = (const float*)d_in[5];
    const float* bu    = (const float*)d_in[6];
    const float* Wc    = (const float*)d_in[7];
    const float* bc    = (const float*)d_in[8];
    const float* Wfs   = (const float*)d_in[9];
    const float* bfs   = (const float*)d_in[10];
    const float* Wdin  = (const float*)d_in[11];
    const float* bdin  = (const float*)d_in[12];
    const float* Wgc   = (const float*)d_in[13];
    const float* bgc   = (const float*)d_in[14];
    const float* Wlout = (const float*)d_in[15];
    const float* blout = (const float*)d_in[16];
    const float* Wro   = (const float*)d_in[17];
    const float* bro   = (const float*)d_in[18];
    const float* pa    = (const float*)d_in[19];

    float* ws = (float*)d_ws;
    float* h      = ws;                 // 131072
    float* Wcomb  = ws + 131072;        // 8448
    float* bcomb  = ws + 139520;        // 128
    float* blout2 = ws + 139648;        // 64
    float* x1b    = ws + 139712;        // 2048
    float* gcp    = ws + 141760;        // 262144
    float* zc     = ws + 403904;        // 675840
    float* ub     = ws + 1079744;       // 131072 -> fp32 end 1210816
    __hip_bfloat16* bfp = (__hip_bfloat16*)(ws + 1210816);
    __hip_bfloat16* adjb  = bfp;               // 4194304
    __hip_bfloat16* adj2b = bfp + 4194304;     // 4194304
    __hip_bfloat16* yb    = bfp + 8388608;     // 262144
    __hip_bfloat16* zb    = bfp + 8650752;     // 675840
    __hip_bfloat16* zcb   = bfp + 9326592;     // 135168 (end 9461760, ~23.8 MB total)

    float* imp  = (float*)d_out;
    float* pred = imp + (size_t)BB * NN * TT;
    float* repr = imp + (size_t)2 * BB * NN * TT;

    hipMemsetAsync(h, 0, (size_t)BB * 64 * NN * sizeof(float), stream);
    hipLaunchKernelGGL(k_prep, dim3(34), dim3(256), 0, stream,
                       Wgc, bgc, Wdin, bdin, Wlout, blout, Wcomb, bcomb, blout2);
    hipLaunchKernelGGL(k_cvt, dim3(4096), dim3(256), 0, stream, adj, adjb);
    hipLaunchKernelGGL(k_a2, dim3(64, 4, 16), dim3(256), 0, stream, adjb, adj2b);

    const dim3 bG(256);
    for (int t = 0; t < TT; ++t) {
        hipLaunchKernelGGL(k_prestep, dim3(8, 128), bG, 0, stream,
                           x, mask, h, Wfs, bfs, Wcomb, bcomb, yb, x1b, pred, t);
        hipLaunchKernelGGL((k_dif<64>), dim3(64, 4), bG, 0, stream,
                           adjb, adjb, yb, 128, 0, 64,
                           gcp, 128, 0, 64, 0,
                           (__hip_bfloat16*)nullptr, 0, 0, 0, 0);
        hipLaunchKernelGGL(k_stepB, dim3(512), bG, 0, stream,
                           gcp, h, Wlout, blout2, pa, Wro, bro, x1b, x, mask,
                           imp, repr, zb, t);
        if (t < TT - 1) {
            hipLaunchKernelGGL((k_dif<66>), dim3(64, 8), bG, 0, stream,
                               adjb, adj2b, zb, 330, 0, 0,
                               (float*)nullptr, 0, 0, 0, 0,
                               zb, 330, 66, 132, 66);
            hipLaunchKernelGGL(k_gates, dim3(8, 64), bG, 0, stream,
                               zb, h, Wr, br, Wu, bu, ub, zc, zcb);
            hipLaunchKernelGGL((k_dif<66>), dim3(64, 8), bG, 0, stream,
                               adjb, adj2b, zcb, 66, 0, 0,
                               zc, 330, 66, 132, 66,
                               (__hip_bfloat16*)nullptr, 0, 0, 0, 0);
            hipLaunchKernelGGL(k_cell, dim3(8, 64), bG, 0, stream, zc, ub, Wc, bc, h);
        }
    }
}

// Round 7
// 863.655 us; speedup vs baseline: 7.3774x; 1.2411x over previous
//
#include <hip/hip_runtime.h>
#include <hip/hip_bf16.h>
#include <cstddef>

#define NN 1024
#define BB 2
#define TT 12
#define ZS 352   // zT/zcT row stride: [h(0..63), x2(64), m(65), pad, 4 blocks @ 68+68b of [hdiff(0..63), x2d(64), md(65), pad], pad..351]

typedef __attribute__((ext_vector_type(8))) short short8;
typedef __attribute__((ext_vector_type(4))) short short4v;
typedef __attribute__((ext_vector_type(4))) float f32x4;
typedef __hip_bfloat16 bf16;

__device__ __forceinline__ float sigmoidf_(float v) { return 1.0f / (1.0f + expf(-v)); }
__device__ __forceinline__ short bf16s(float f) { bf16 h = __float2bfloat16(f); return *reinterpret_cast<short*>(&h); }

// ---------------- one-time weight prep ----------------
// Wcomb fold (fp32), bcomb, blout2, Wpre[144][64] bf16, Wrub[128][352] bf16, Wcb[64][352] bf16
__device__ __forceinline__ float mapcol(const float* src, int c) {
    if (c < 64) return src[2 + c];
    if (c == 64) return src[0];
    if (c == 65) return src[1];
    if (c < 68 || c >= 340) return 0.f;
    const int d = c - 68, bk = d / 68, off = d % 68;
    if (off < 64) return src[66 + bk * 66 + 2 + off];
    if (off == 64) return src[66 + bk * 66];
    if (off == 65) return src[66 + bk * 66 + 1];
    return 0.f;
}

__global__ __launch_bounds__(256) void k_prep(
    const float* __restrict__ Wgc, const float* __restrict__ bgc,
    const float* __restrict__ Wdin, const float* __restrict__ bdin,
    const float* __restrict__ Wlout, const float* __restrict__ blout,
    const float* __restrict__ Wfs,
    const float* __restrict__ Wr, const float* __restrict__ Wu, const float* __restrict__ Wc,
    float* __restrict__ Wcomb, float* __restrict__ bcomb, float* __restrict__ blout2,
    bf16* __restrict__ Wpre, bf16* __restrict__ Wrub, bf16* __restrict__ Wcb)
{
    const int idx = blockIdx.x * 256 + threadIdx.x;
    if (idx < 8448) {
        const int o = idx / 66, k = idx % 66;
        const float* g = Wgc + (size_t)(o & 63) * 128 + (o >> 6) * 64;
        float a = 0.f;
#pragma unroll 8
        for (int c = 0; c < 64; ++c) a += g[c] * Wdin[c * 66 + k];
        Wcomb[idx] = a;
    } else if (idx < 8576) {
        const int o = idx - 8448;
        const float* g = Wgc + (size_t)(o & 63) * 128 + (o >> 6) * 64;
        float a = 0.f;
#pragma unroll 8
        for (int c = 0; c < 64; ++c) a += g[c] * bdin[c];
        bcomb[o] = a;
    } else if (idx < 8640) {
        const int oc = idx - 8576;
        float a = blout[oc];
#pragma unroll 8
        for (int j = 0; j < 64; ++j) a += Wlout[(size_t)oc * 128 + j] * bgc[j];
        blout2[oc] = a;
    } else if (idx < 17856) {
        const int j = idx - 8640, r = j >> 6, k = j & 63;
        float v = 0.f;
        if (r == 0) v = Wfs[k];
        else if (r <= 128) {
            const int o = r - 1;
            const float* g = Wgc + (size_t)(o & 63) * 128 + (o >> 6) * 64;
#pragma unroll 8
            for (int c = 0; c < 64; ++c) v += g[c] * Wdin[c * 66 + 2 + k];
        }
        Wpre[j] = __float2bfloat16(v);
    } else if (idx < 62912) {
        const int j = idx - 17856, r = j / 352, c = j % 352;
        const float* src = (r < 64) ? (Wr + (size_t)r * 330) : (Wu + (size_t)(r - 64) * 330);
        Wrub[j] = __float2bfloat16(mapcol(src, c));
    } else if (idx < 85440) {
        const int j = idx - 62912, r = j / 352, c = j % 352;
        Wcb[j] = __float2bfloat16(mapcol(Wc + (size_t)r * 330, c));
    }
}

// ---------------- adj fp32 -> bf16 (adjb) + bf16 transposed (adjtb) ----------------
__global__ __launch_bounds__(256) void k_cvtT(const float* __restrict__ adj,
                                              bf16* __restrict__ adjb, bf16* __restrict__ adjtb)
{
    const int sb = blockIdx.z;
    const int r0 = blockIdx.y * 64, c0 = blockIdx.x * 64;
    const float* A = adj + ((size_t)sb << 20);
    __shared__ short tile[64][72];
    const int tr = threadIdx.x >> 4, tc = (threadIdx.x & 15) * 4;
#pragma unroll
    for (int i = 0; i < 4; ++i) {
        const int r = tr + i * 16;
        float4 v = *reinterpret_cast<const float4*>(&A[(size_t)(r0 + r) * NN + c0 + tc]);
        short4v o = { bf16s(v.x), bf16s(v.y), bf16s(v.z), bf16s(v.w) };
        *reinterpret_cast<short4v*>(&adjb[((size_t)sb << 20) + (size_t)(r0 + r) * NN + c0 + tc]) = o;
        tile[r][tc + 0] = o.x; tile[r][tc + 1] = o.y; tile[r][tc + 2] = o.z; tile[r][tc + 3] = o.w;
    }
    __syncthreads();
#pragma unroll
    for (int i = 0; i < 4; ++i) {
        const int v = tr + i * 16;  // column of tile -> row of adjtb
        short4v o = { tile[tc + 0][v], tile[tc + 1][v], tile[tc + 2][v], tile[tc + 3][v] };
        *reinterpret_cast<short4v*>(&adjtb[((size_t)sb << 20) + (size_t)(c0 + v) * NN + r0 + tc]) = o;
    }
}

// ---------------- A^2 via dual-row-major MFMA (no LDS) ----------------
// adj2b[sb][w][v] = sum_k adjb[sb][w][k] * adjtb[sb][v][k]
__global__ __launch_bounds__(256) void k_a2(const bf16* __restrict__ adjb,
                                            const bf16* __restrict__ adjtb,
                                            bf16* __restrict__ adj2b)
{
    const int sb = blockIdx.z;
    const int wave = threadIdx.x >> 6, lane = threadIdx.x & 63;
    const int lr = lane & 15, lq = lane >> 4;
    const int v0 = blockIdx.x * 64 + wave * 16;
    const int w0 = blockIdx.y * 64;
    const bf16* AT = adjtb + ((size_t)sb << 20) + (size_t)(v0 + lr) * NN + lq * 8;
    const bf16* Ar = adjb + ((size_t)sb << 20) + (size_t)(w0 + lr) * NN + lq * 8;
    f32x4 acc[4];
#pragma unroll
    for (int m = 0; m < 4; ++m) acc[m] = (f32x4){0.f, 0.f, 0.f, 0.f};
#pragma unroll 4
    for (int k0 = 0; k0 < NN; k0 += 32) {
        short8 bfr = *reinterpret_cast<const short8*>(AT + k0);
#pragma unroll
        for (int m = 0; m < 4; ++m) {
            short8 af = *reinterpret_cast<const short8*>(Ar + (size_t)m * 16 * NN + k0);
            acc[m] = __builtin_amdgcn_mfma_f32_16x16x32_bf16(af, bfr, acc[m], 0, 0, 0);
        }
    }
    bf16* D = adj2b + ((size_t)sb << 20);
#pragma unroll
    for (int m = 0; m < 4; ++m)
#pragma unroll
        for (int q = 0; q < 4; ++q)
            D[(size_t)(w0 + m * 16 + lq * 4 + q) * NN + v0 + lr] = __float2bfloat16(acc[m][q]);
}

// ---------------- pre: MFMA [Wfs;Wcomb_h] . h  + epilogue (xs1, x1, y) ----------------
__global__ __launch_bounds__(64) void k_pre(
    const bf16* __restrict__ Wpre, const bf16* __restrict__ zT,
    const float* __restrict__ Wcomb, const float* __restrict__ bcomb,
    const float* __restrict__ bfsp,
    const float* __restrict__ x, const int* __restrict__ mask,
    bf16* __restrict__ yb, float* __restrict__ x1b, float* __restrict__ pred, int t)
{
    const int lane = threadIdx.x & 63, lr = lane & 15, lq = lane >> 4;
    const int p = blockIdx.x * 16 + lr;
    const bf16* B = zT + (size_t)p * ZS;
    f32x4 acc[9];
#pragma unroll
    for (int m = 0; m < 9; ++m) acc[m] = (f32x4){0.f, 0.f, 0.f, 0.f};
#pragma unroll
    for (int ks = 0; ks < 2; ++ks) {
        short8 bfr = *reinterpret_cast<const short8*>(B + ks * 32 + lq * 8);
#pragma unroll
        for (int m = 0; m < 9; ++m) {
            short8 af = *reinterpret_cast<const short8*>(Wpre + (size_t)(m * 16 + lr) * 64 + ks * 32 + lq * 8);
            acc[m] = __builtin_amdgcn_mfma_f32_16x16x32_bf16(af, bfr, acc[m], 0, 0, 0);
        }
    }
    const int b = p >> 10, n = p & (NN - 1);
    const size_t xi = (size_t)p * TT + t;
    const float xs1v = acc[0][0] + bfsp[0];
    const float xs1 = __shfl(xs1v, lr);
    const int mi = mask[xi];
    const float mf = (float)mi;
    const float x1 = mi ? x[xi] : xs1;
    if (lq == 0) { pred[xi] = xs1; x1b[p] = x1; }
#pragma unroll
    for (int m = 0; m < 9; ++m)
#pragma unroll
        for (int q = 0; q < 4; ++q) {
            const int o = m * 16 + lq * 4 + q - 1;
            if (o >= 0 && o < 128) {
                const float val = acc[m][q] + Wcomb[o * 66] * x1 + Wcomb[o * 66 + 1] * mf + bcomb[o];
                yb[(size_t)(b * 128 + o) * NN + n] = __float2bfloat16(val);
            }
        }
}

// ---------------- diffusion (split-K 4 waves, node-major output) ----------------
// mode 0 (difA): combos 0..3 = yb -> gcT (fp32); combos 4..11 = zb h-rows -> zT diff slots (bf16)
// mode 1 (difB): combos 0..7 = zcb rh-rows -> zcT diff slots (bf16)
__global__ __launch_bounds__(256) void k_difN(
    int mode, const bf16* __restrict__ adjb, const bf16* __restrict__ adj2b,
    const bf16* __restrict__ yb, const bf16* __restrict__ zb, const bf16* __restrict__ zcb,
    float* __restrict__ gcT, bf16* __restrict__ zT, bf16* __restrict__ zcT)
{
    const int combo = blockIdx.y;
    const int wave = threadIdx.x >> 6, lane = threadIdx.x & 63;
    const int lr = lane & 15, lq = lane >> 4;
    const int n0 = blockIdx.x * 16;

    int s, b, ord; const bf16* X; bool toGc = false;
    if (mode == 0 && combo < 4) {
        s = combo >> 1; b = combo & 1; ord = 0; toGc = true;
        X = yb + ((size_t)(b * 128 + s * 64)) * NN;
    } else {
        const int i = (mode == 0) ? combo - 4 : combo;
        b = i & 1; s = (i >> 1) & 1; ord = i >> 2;
        X = ((mode == 0) ? zb : zcb) + ((size_t)b * 66) * NN;
    }
    const int sb = s * 2 + b;
    const bf16* M = (ord ? adj2b : adjb) + ((size_t)sb << 20);
    const bf16* A = M + (size_t)(n0 + lr) * NN + lq * 8;
    const bf16* Xp = X + (size_t)lr * NN + lq * 8;

    f32x4 acc[4];
#pragma unroll
    for (int m = 0; m < 4; ++m) acc[m] = (f32x4){0.f, 0.f, 0.f, 0.f};
    const int vbeg = wave * 256;
#pragma unroll 4
    for (int i = 0; i < 8; ++i) {
        const int v0 = vbeg + i * 32;
        short8 bfr = *reinterpret_cast<const short8*>(A + v0);
#pragma unroll
        for (int m = 0; m < 4; ++m) {
            short8 af = *reinterpret_cast<const short8*>(Xp + (size_t)m * 16 * NN + v0);
            acc[m] = __builtin_amdgcn_mfma_f32_16x16x32_bf16(af, bfr, acc[m], 0, 0, 0);
        }
    }
    __shared__ f32x4 red[3][4][64];
    if (wave > 0) {
#pragma unroll
        for (int m = 0; m < 4; ++m) red[wave - 1][m][lane] = acc[m];
    }
    __syncthreads();
    if (wave == 0) {
#pragma unroll
        for (int m = 0; m < 4; ++m)
            acc[m] += red[0][m][lane] + red[1][m][lane] + red[2][m][lane];
        const int p = b * NN + n0 + lr;
        if (toGc) {
#pragma unroll
            for (int m = 0; m < 4; ++m)
                *reinterpret_cast<f32x4*>(&gcT[(size_t)p * 128 + s * 64 + m * 16 + lq * 4]) = acc[m];
        } else {
            bf16* dst = ((mode == 0) ? zT : zcT) + (size_t)p * ZS + 68 + (s * 2 + ord) * 68;
#pragma unroll
            for (int m = 0; m < 4; ++m) {
                short4v o = { bf16s(acc[m][0]), bf16s(acc[m][1]), bf16s(acc[m][2]), bf16s(acc[m][3]) };
                *reinterpret_cast<short4v*>(dst + m * 16 + lq * 4) = o;
            }
        }
    }
}

// ---------------- dif2: diffuse x2,m (2 ch) -> both zT and zcT slots ----------------
__global__ __launch_bounds__(256) void k_dif2(
    const bf16* __restrict__ adjb, const bf16* __restrict__ adj2b,
    const bf16* __restrict__ zb, bf16* __restrict__ zT, bf16* __restrict__ zcT)
{
    const int i = blockIdx.y;
    const int b = i & 1, s = (i >> 1) & 1, ord = i >> 2;
    const int sb = s * 2 + b;
    const int wave = threadIdx.x >> 6, lane = threadIdx.x & 63;
    const int lr = lane & 15, lq = lane >> 4;
    const int n0 = blockIdx.x * 16;
    const bf16* M = (ord ? adj2b : adjb) + ((size_t)sb << 20);
    const bf16* A = M + (size_t)(n0 + lr) * NN + lq * 8;
    const bf16* Xp = zb + ((size_t)(b * 66 + 64) + lr) * NN + lq * 8;

    f32x4 acc = (f32x4){0.f, 0.f, 0.f, 0.f};
    const short8 zsh = {0, 0, 0, 0, 0, 0, 0, 0};
    const int vbeg = wave * 256;
#pragma unroll 4
    for (int i2 = 0; i2 < 8; ++i2) {
        const int v0 = vbeg + i2 * 32;
        short8 bfr = *reinterpret_cast<const short8*>(A + v0);
        short8 af = (lr < 2) ? *reinterpret_cast<const short8*>(Xp + v0) : zsh;
        acc = __builtin_amdgcn_mfma_f32_16x16x32_bf16(af, bfr, acc, 0, 0, 0);
    }
    __shared__ f32x4 red2[3][64];
    if (wave > 0) red2[wave - 1][lane] = acc;
    __syncthreads();
    if (wave == 0 && lq == 0) {
        acc += red2[0][lane] + red2[1][lane] + red2[2][lane];
        const int p = b * NN + n0 + lr;
        const size_t off = (size_t)p * ZS + 68 + (s * 2 + ord) * 68 + 64;
#pragma unroll
        for (int q = 0; q < 2; ++q) {
            const bf16 v = __float2bfloat16(acc[q]);
            zT[off + q] = v; zcT[off + q] = v;
        }
    }
}

// ---------------- stepB: dec2 + xs2 fused (wave-per-node) ----------------
__global__ __launch_bounds__(256) void k_stepB(
    const float* __restrict__ gcT, const float* __restrict__ hTf,
    const float* __restrict__ Wlout, const float* __restrict__ blout2,
    const float* __restrict__ prelu_a, const float* __restrict__ Wro,
    const float* __restrict__ bro, const float* __restrict__ x1b,
    const int* __restrict__ mask,
    float* __restrict__ imp, float* __restrict__ repr,
    bf16* __restrict__ zb, bf16* __restrict__ zcb,
    bf16* __restrict__ zT, bf16* __restrict__ zcT, int t)
{
    const int wv = threadIdx.x >> 6, lane = threadIdx.x & 63;
    const int p = blockIdx.x * 4 + wv;
    const int b = p >> 10, n = p & (NN - 1);
    __shared__ float gl[4][64], hl[4][64];
    const float g = gcT[(size_t)p * 128 + lane] + gcT[(size_t)p * 128 + 64 + lane];
    const float hv = hTf[(size_t)p * 64 + lane];
    gl[wv][lane] = g;
    hl[wv][lane] = hv;
    __syncthreads();
    const float* w = Wlout + (size_t)lane * 128;
    float a = 0.f;
#pragma unroll 8
    for (int j = 0; j < 64; ++j)
        a += w[j] * gl[wv][j] + w[64 + j] * hl[wv][j];
    float v = a + blout2[lane];
    v = (v >= 0.f) ? v : prelu_a[0] * v;
    repr[(((size_t)b * 128 + lane) * NN + n) * TT + t] = v;
    repr[(((size_t)b * 128 + 64 + lane) * NN + n) * TT + t] = hv;
    float s = Wro[lane] * v + Wro[64 + lane] * hv;
#pragma unroll
    for (int off = 32; off > 0; off >>= 1) s += __shfl_xor(s, off);
    if (lane == 0) {
        const float xs2 = s + bro[0];
        const size_t xi = (size_t)p * TT + t;
        imp[xi] = xs2;
        const int mi = mask[xi];
        const float x2 = mi ? x1b[p] : xs2;
        const bf16 x2b = __float2bfloat16(x2);
        const bf16 mb = __float2bfloat16((float)mi);
        zb[((size_t)b * 66 + 64) * NN + n] = x2b;
        zb[((size_t)b * 66 + 65) * NN + n] = mb;
        zcb[((size_t)b * 66 + 64) * NN + n] = x2b;
        zcb[((size_t)b * 66 + 65) * NN + n] = mb;
        zT[(size_t)p * ZS + 64] = x2b; zT[(size_t)p * ZS + 65] = mb;
        zcT[(size_t)p * ZS + 64] = x2b; zcT[(size_t)p * ZS + 65] = mb;
    }
}

// ---------------- gates: MFMA [Wr;Wu].zT + epilogue ----------------
__global__ __launch_bounds__(64) void k_gates(
    const bf16* __restrict__ Wrub, const bf16* __restrict__ zT,
    const float* __restrict__ br, const float* __restrict__ bu,
    const float* __restrict__ hTf,
    float* __restrict__ uT, bf16* __restrict__ zcb, bf16* __restrict__ zcT)
{
    const int lane = threadIdx.x & 63, lr = lane & 15, lq = lane >> 4;
    const int p = blockIdx.x * 16 + lr;
    const bf16* B = zT + (size_t)p * ZS;
    f32x4 acc[8];
#pragma unroll
    for (int m = 0; m < 8; ++m) acc[m] = (f32x4){0.f, 0.f, 0.f, 0.f};
#pragma unroll 2
    for (int ks = 0; ks < 11; ++ks) {
        short8 bfr = *reinterpret_cast<const short8*>(B + ks * 32 + lq * 8);
#pragma unroll
        for (int m = 0; m < 8; ++m) {
            short8 af = *reinterpret_cast<const short8*>(Wrub + (size_t)(m * 16 + lr) * ZS + ks * 32 + lq * 8);
            acc[m] = __builtin_amdgcn_mfma_f32_16x16x32_bf16(af, bfr, acc[m], 0, 0, 0);
        }
    }
    const int b = p >> 10, n = p & (NN - 1);
#pragma unroll
    for (int m = 0; m < 4; ++m) {
        f32x4 uq;
        short4v rq;
#pragma unroll
        for (int q = 0; q < 4; ++q) {
            const int oc = m * 16 + lq * 4 + q;
            const float rv = sigmoidf_(acc[m][q] + br[oc]);
            const float uv = sigmoidf_(acc[m + 4][q] + bu[oc]);
            const float hv = hTf[(size_t)p * 64 + oc];
            const float rh = rv * hv;
            uq[q] = uv;
            rq[q] = bf16s(rh);
            zcb[((size_t)b * 66 + oc) * NN + n] = __float2bfloat16(rh);
        }
        *reinterpret_cast<f32x4*>(&uT[(size_t)p * 64 + m * 16 + lq * 4]) = uq;
        *reinterpret_cast<short4v*>(&zcT[(size_t)p * ZS + m * 16 + lq * 4]) = rq;
    }
}

// ---------------- cell: MFMA Wc.zcT + h update ----------------
__global__ __launch_bounds__(64) void k_cell(
    const bf16* __restrict__ Wcb, const bf16* __restrict__ zcT,
    const float* __restrict__ bc, const float* __restrict__ uT,
    float* __restrict__ hTf, bf16* __restrict__ zT, bf16* __restrict__ zb)
{
    const int lane = threadIdx.x & 63, lr = lane & 15, lq = lane >> 4;
    const int p = blockIdx.x * 16 + lr;
    const bf16* B = zcT + (size_t)p * ZS;
    f32x4 acc[4];
#pragma unroll
    for (int m = 0; m < 4; ++m) acc[m] = (f32x4){0.f, 0.f, 0.f, 0.f};
#pragma unroll 2
    for (int ks = 0; ks < 11; ++ks) {
        short8 bfr = *reinterpret_cast<const short8*>(B + ks * 32 + lq * 8);
#pragma unroll
        for (int m = 0; m < 4; ++m) {
            short8 af = *reinterpret_cast<const short8*>(Wcb + (size_t)(m * 16 + lr) * ZS + ks * 32 + lq * 8);
            acc[m] = __builtin_amdgcn_mfma_f32_16x16x32_bf16(af, bfr, acc[m], 0, 0, 0);
        }
    }
    const int b = p >> 10, n = p & (NN - 1);
#pragma unroll
    for (int m = 0; m < 4; ++m) {
        f32x4 hq;
        short4v hb;
#pragma unroll
        for (int q = 0; q < 4; ++q) {
            const int oc = m * 16 + lq * 4 + q;
            const float cv = tanhf(acc[m][q] + bc[oc]);
            const float uv = uT[(size_t)p * 64 + oc];
            const float ho = hTf[(size_t)p * 64 + oc];
            const float hn = uv * ho + (1.f - uv) * cv;
            hq[q] = hn;
            hb[q] = bf16s(hn);
            zb[((size_t)b * 66 + oc) * NN + n] = __float2bfloat16(hn);
        }
        *reinterpret_cast<f32x4*>(&hTf[(size_t)p * 64 + m * 16 + lq * 4]) = hq;
        *reinterpret_cast<short4v*>(&zT[(size_t)p * ZS + m * 16 + lq * 4]) = hb;
    }
}

extern "C" void kernel_launch(void* const* d_in, const int* in_sizes, int n_in,
                              void* d_out, int out_size, void* d_ws, size_t ws_size,
                              hipStream_t stream)
{
    const float* x     = (const float*)d_in[0];
    const int*   mask  = (const int*)  d_in[1];
    const float* adj   = (const float*)d_in[2];
    const float* Wr    = (const float*)d_in[3];
    const float* br    = (const float*)d_in[4];
    const float* Wu    = (const float*)d_in[5];
    const float* bu    = (const float*)d_in[6];
    const float* Wc    = (const float*)d_in[7];
    const float* bc    = (const float*)d_in[8];
    const float* Wfs   = (const float*)d_in[9];
    const float* bfs   = (const float*)d_in[10];
    const float* Wdin  = (const float*)d_in[11];
    const float* bdin  = (const float*)d_in[12];
    const float* Wgc   = (const float*)d_in[13];
    const float* bgc   = (const float*)d_in[14];
    const float* Wlout = (const float*)d_in[15];
    const float* blout = (const float*)d_in[16];
    const float* Wro   = (const float*)d_in[17];
    const float* bro   = (const float*)d_in[18];
    const float* pa    = (const float*)d_in[19];

    float* ws = (float*)d_ws;
    float* Wcomb  = ws + 0;          // 8448
    float* bcomb  = ws + 8448;       // 128
    float* blout2 = ws + 8576;       // 64
    float* x1b    = ws + 8640;       // 2048
    float* gcT    = ws + 10688;      // 262144
    float* uT     = ws + 272832;     // 131072
    float* hTf    = ws + 403904;     // 131072   <- memset region start
    bf16* bfp   = (bf16*)(ws + 534976);
    bf16* zb    = bfp + 0;           // 135168
    bf16* zcb   = bfp + 135168;      // 135168
    bf16* zT    = bfp + 270336;      // 720896
    bf16* zcT   = bfp + 991232;      // 720896   <- memset region end (bfp+1712128)
    bf16* adjb  = bfp + 1712128;     // 4194304
    bf16* adjtb = bfp + 5906432;     // 4194304
    bf16* adj2b = bfp + 10100736;    // 4194304
    bf16* yb    = bfp + 14295040;    // 262144
    bf16* Wpre  = bfp + 14557184;    // 9216
    bf16* Wrub  = bfp + 14566400;    // 45056
    bf16* Wcb   = bfp + 14611456;    // 22528

    float* imp  = (float*)d_out;
    float* pred = imp + (size_t)BB * NN * TT;
    float* repr = imp + (size_t)2 * BB * NN * TT;

    // zero h (fp32 + bf16 mirrors) and all z staging (incl. pad columns) in one shot
    hipMemsetAsync(hTf, 0, 131072 * 4 + (size_t)1712128 * 2, stream);
    hipLaunchKernelGGL(k_prep, dim3(334), dim3(256), 0, stream,
                       Wgc, bgc, Wdin, bdin, Wlout, blout, Wfs, Wr, Wu, Wc,
                       Wcomb, bcomb, blout2, Wpre, Wrub, Wcb);
    hipLaunchKernelGGL(k_cvtT, dim3(16, 16, 4), dim3(256), 0, stream, adj, adjb, adjtb);
    hipLaunchKernelGGL(k_a2, dim3(16, 16, 4), dim3(256), 0, stream, adjb, adjtb, adj2b);

    for (int t = 0; t < TT; ++t) {
        hipLaunchKernelGGL(k_pre, dim3(128), dim3(64), 0, stream,
                           Wpre, zT, Wcomb, bcomb, bfs, x, mask, yb, x1b, pred, t);
        const int ncombo = (t < TT - 1) ? 12 : 4;
        hipLaunchKernelGGL(k_difN, dim3(64, ncombo), dim3(256), 0, stream,
                           0, adjb, adj2b, yb, zb, zcb, gcT, zT, zcT);
        hipLaunchKernelGGL(k_stepB, dim3(512), dim3(256), 0, stream,
                           gcT, hTf, Wlout, blout2, pa, Wro, bro, x1b, mask,
                           imp, repr, zb, zcb, zT, zcT, t);
        if (t < TT - 1) {
            hipLaunchKernelGGL(k_dif2, dim3(64, 8), dim3(256), 0, stream,
                               adjb, adj2b, zb, zT, zcT);
            hipLaunchKernelGGL(k_gates, dim3(128), dim3(64), 0, stream,
                               Wrub, zT, br, bu, hTf, uT, zcb, zcT);
            hipLaunchKernelGGL(k_difN, dim3(64, 8), dim3(256), 0, stream,
                               1, adjb, adj2b, yb, zb, zcb, gcT, zT, zcT);
            hipLaunchKernelGGL(k_cell, dim3(128), dim3(64), 0, stream,
                               Wcb, zcT, bc, uT, hTf, zT, zb);
        }
    }
}

// Round 8
// 768.144 us; speedup vs baseline: 8.2947x; 1.1243x over previous
//
#include <hip/hip_runtime.h>
#include <hip/hip_bf16.h>
#include <cstddef>

#define NN 1024
#define BB 2
#define TT 12
#define ZS 352   // zT/zcT row stride: [h(0..63), x2(64), m(65), pad, 4 slots @68: [hdiff(0..63), x2d(64), md(65), pad]]

typedef __attribute__((ext_vector_type(8))) short short8;
typedef __attribute__((ext_vector_type(4))) short short4v;
typedef __attribute__((ext_vector_type(4))) float f32x4;
typedef __hip_bfloat16 bf16;

__device__ __forceinline__ float sigmoidf_(float v) { return 1.0f / (1.0f + expf(-v)); }
__device__ __forceinline__ short bf16s(float f) { bf16 h = __float2bfloat16(f); return *reinterpret_cast<short*>(&h); }

// ---------------- one-time weight prep ----------------
__device__ __forceinline__ float mapcol(const float* src, int c) {
    if (c < 64) return src[2 + c];
    if (c == 64) return src[0];
    if (c == 65) return src[1];
    if (c < 68 || c >= 340) return 0.f;
    const int d = c - 68, bk = d / 68, off = d % 68;
    if (off < 64) return src[66 + bk * 66 + 2 + off];
    if (off == 64) return src[66 + bk * 66];
    if (off == 65) return src[66 + bk * 66 + 1];
    return 0.f;
}

__global__ __launch_bounds__(256) void k_prep(
    const float* __restrict__ Wgc, const float* __restrict__ bgc,
    const float* __restrict__ Wdin, const float* __restrict__ bdin,
    const float* __restrict__ Wlout, const float* __restrict__ blout,
    const float* __restrict__ Wfs,
    const float* __restrict__ Wr, const float* __restrict__ Wu, const float* __restrict__ Wc,
    float* __restrict__ Wcomb, float* __restrict__ bcomb, float* __restrict__ blout2,
    bf16* __restrict__ Wpre, bf16* __restrict__ Wrub, bf16* __restrict__ Wcb)
{
    const int idx = blockIdx.x * 256 + threadIdx.x;
    if (idx < 8448) {
        const int o = idx / 66, k = idx % 66;
        const float* g = Wgc + (size_t)(o & 63) * 128 + (o >> 6) * 64;
        float a = 0.f;
#pragma unroll 8
        for (int c = 0; c < 64; ++c) a += g[c] * Wdin[c * 66 + k];
        Wcomb[idx] = a;
    } else if (idx < 8576) {
        const int o = idx - 8448;
        const float* g = Wgc + (size_t)(o & 63) * 128 + (o >> 6) * 64;
        float a = 0.f;
#pragma unroll 8
        for (int c = 0; c < 64; ++c) a += g[c] * bdin[c];
        bcomb[o] = a;
    } else if (idx < 8640) {
        const int oc = idx - 8576;
        float a = blout[oc];
#pragma unroll 8
        for (int j = 0; j < 64; ++j) a += Wlout[(size_t)oc * 128 + j] * bgc[j];
        blout2[oc] = a;
    } else if (idx < 17856) {
        const int j = idx - 8640, r = j >> 6, k = j & 63;
        float v = 0.f;
        if (r == 0) v = Wfs[k];
        else if (r <= 128) {
            const int o = r - 1;
            const float* g = Wgc + (size_t)(o & 63) * 128 + (o >> 6) * 64;
#pragma unroll 8
            for (int c = 0; c < 64; ++c) v += g[c] * Wdin[c * 66 + 2 + k];
        }
        Wpre[j] = __float2bfloat16(v);
    } else if (idx < 62912) {
        const int j = idx - 17856, r = j / 352, c = j % 352;
        const float* src = (r < 64) ? (Wr + (size_t)r * 330) : (Wu + (size_t)(r - 64) * 330);
        Wrub[j] = __float2bfloat16(mapcol(src, c));
    } else if (idx < 85440) {
        const int j = idx - 62912, r = j / 352, c = j % 352;
        Wcb[j] = __float2bfloat16(mapcol(Wc + (size_t)r * 330, c));
    }
}

// ---------------- adj fp32 -> bf16 (adjb) + transposed (adjtb) ----------------
__global__ __launch_bounds__(256) void k_cvtT(const float* __restrict__ adj,
                                              bf16* __restrict__ adjb, bf16* __restrict__ adjtb)
{
    const int sb = blockIdx.z;
    const int r0 = blockIdx.y * 64, c0 = blockIdx.x * 64;
    const float* A = adj + ((size_t)sb << 20);
    __shared__ short tile[64][72];
    const int tr = threadIdx.x >> 4, tc = (threadIdx.x & 15) * 4;
#pragma unroll
    for (int i = 0; i < 4; ++i) {
        const int r = tr + i * 16;
        float4 v = *reinterpret_cast<const float4*>(&A[(size_t)(r0 + r) * NN + c0 + tc]);
        short4v o = { bf16s(v.x), bf16s(v.y), bf16s(v.z), bf16s(v.w) };
        *reinterpret_cast<short4v*>(&adjb[((size_t)sb << 20) + (size_t)(r0 + r) * NN + c0 + tc]) = o;
        tile[r][tc + 0] = o.x; tile[r][tc + 1] = o.y; tile[r][tc + 2] = o.z; tile[r][tc + 3] = o.w;
    }
    __syncthreads();
#pragma unroll
    for (int i = 0; i < 4; ++i) {
        const int v = tr + i * 16;
        short4v o = { tile[tc + 0][v], tile[tc + 1][v], tile[tc + 2][v], tile[tc + 3][v] };
        *reinterpret_cast<short4v*>(&adjtb[((size_t)sb << 20) + (size_t)(c0 + v) * NN + r0 + tc]) = o;
    }
}

// ---------------- A^2: 64x32 per wave, acc[4][2], 8 MFMA : 6 loads ----------------
// adj2b[sb][w][v] = sum_k adjb[sb][w][k] * adjtb[sb][v][k]
// grid (8 v-tiles of 128, 16 w-tiles of 64, 4 sb), block 256 = 4 waves (v-quarters)
__global__ __launch_bounds__(256) void k_a2(const bf16* __restrict__ adjb,
                                            const bf16* __restrict__ adjtb,
                                            bf16* __restrict__ adj2b)
{
    const int sb = blockIdx.z;
    const int wave = threadIdx.x >> 6, lane = threadIdx.x & 63;
    const int lr = lane & 15, lq = lane >> 4;
    const int v0 = blockIdx.x * 128 + wave * 32;
    const int w0 = blockIdx.y * 64;
    const bf16* AT = adjtb + ((size_t)sb << 20) + (size_t)(v0 + lr) * NN + lq * 8;
    const bf16* Ar = adjb + ((size_t)sb << 20) + (size_t)(w0 + lr) * NN + lq * 8;
    f32x4 acc[4][2];
#pragma unroll
    for (int m = 0; m < 4; ++m)
#pragma unroll
        for (int nb = 0; nb < 2; ++nb) acc[m][nb] = (f32x4){0.f, 0.f, 0.f, 0.f};
#pragma unroll 2
    for (int k0 = 0; k0 < NN; k0 += 32) {
        short8 bfr[2], af[4];
#pragma unroll
        for (int nb = 0; nb < 2; ++nb)
            bfr[nb] = *reinterpret_cast<const short8*>(AT + (size_t)nb * 16 * NN + k0);
#pragma unroll
        for (int m = 0; m < 4; ++m)
            af[m] = *reinterpret_cast<const short8*>(Ar + (size_t)m * 16 * NN + k0);
#pragma unroll
        for (int m = 0; m < 4; ++m)
#pragma unroll
            for (int nb = 0; nb < 2; ++nb)
                acc[m][nb] = __builtin_amdgcn_mfma_f32_16x16x32_bf16(af[m], bfr[nb], acc[m][nb], 0, 0, 0);
    }
    bf16* D = adj2b + ((size_t)sb << 20);
#pragma unroll
    for (int m = 0; m < 4; ++m)
#pragma unroll
        for (int nb = 0; nb < 2; ++nb)
#pragma unroll
            for (int q = 0; q < 4; ++q)
                D[(size_t)(w0 + m * 16 + lq * 4 + q) * NN + v0 + nb * 16 + lr] = __float2bfloat16(acc[m][nb][q]);
}

// ---------------- pre (standalone, t=0): MFMA [Wfs;Wcomb_h].h + epilogue ----------------
__global__ __launch_bounds__(64) void k_pre(
    const bf16* __restrict__ Wpre, const bf16* __restrict__ zT,
    const float* __restrict__ Wcomb, const float* __restrict__ bcomb,
    const float* __restrict__ bfsp,
    const float* __restrict__ x, const int* __restrict__ mask,
    bf16* __restrict__ yb, float* __restrict__ x1b, float* __restrict__ pred, int t)
{
    const int lane = threadIdx.x & 63, lr = lane & 15, lq = lane >> 4;
    const int p = blockIdx.x * 16 + lr;
    const bf16* B = zT + (size_t)p * ZS;
    f32x4 acc[9];
#pragma unroll
    for (int m = 0; m < 9; ++m) acc[m] = (f32x4){0.f, 0.f, 0.f, 0.f};
#pragma unroll
    for (int ks = 0; ks < 2; ++ks) {
        short8 bfr = *reinterpret_cast<const short8*>(B + ks * 32 + lq * 8);
#pragma unroll
        for (int m = 0; m < 9; ++m) {
            short8 af = *reinterpret_cast<const short8*>(Wpre + (size_t)(m * 16 + lr) * 64 + ks * 32 + lq * 8);
            acc[m] = __builtin_amdgcn_mfma_f32_16x16x32_bf16(af, bfr, acc[m], 0, 0, 0);
        }
    }
    const int b = p >> 10, n = p & (NN - 1);
    const size_t xi = (size_t)p * TT + t;
    const float xs1v = acc[0][0] + bfsp[0];
    const float xs1 = __shfl(xs1v, lr);
    const int mi = mask[xi];
    const float mf = (float)mi;
    const float x1 = mi ? x[xi] : xs1;
    if (lq == 0) { pred[xi] = xs1; x1b[p] = x1; }
#pragma unroll
    for (int m = 0; m < 9; ++m)
#pragma unroll
        for (int q = 0; q < 4; ++q) {
            const int o = m * 16 + lq * 4 + q - 1;
            if (o >= 0 && o < 128) {
                const float val = acc[m][q] + Wcomb[o * 66] * x1 + Wcomb[o * 66 + 1] * mf + bcomb[o];
                yb[(size_t)(b * 128 + o) * NN + n] = __float2bfloat16(val);
            }
        }
}

// ---------------- diffusion: 2 n-tiles/wave, split-K 4 waves ----------------
// mode 0: combos 0..3 = yb -> gcT (fp32); combos 4..11 = zb h-rows -> zT slots (bf16)
// mode 1: combos 0..7 = zcb rh-rows -> zcT slots (bf16)
__global__ __launch_bounds__(256) void k_difN(
    int mode, const bf16* __restrict__ adjb, const bf16* __restrict__ adj2b,
    const bf16* __restrict__ yb, const bf16* __restrict__ zb, const bf16* __restrict__ zcb,
    float* __restrict__ gcT, bf16* __restrict__ zT, bf16* __restrict__ zcT)
{
    const int combo = blockIdx.y;
    const int wave = threadIdx.x >> 6, lane = threadIdx.x & 63;
    const int lr = lane & 15, lq = lane >> 4;
    const int n0 = blockIdx.x * 32;

    int s, b, ord; const bf16* X; bool toGc = false;
    if (mode == 0 && combo < 4) {
        s = combo >> 1; b = combo & 1; ord = 0; toGc = true;
        X = yb + ((size_t)(b * 128 + s * 64)) * NN;
    } else {
        const int i = (mode == 0) ? combo - 4 : combo;
        b = i & 1; s = (i >> 1) & 1; ord = i >> 2;
        X = ((mode == 0) ? zb : zcb) + ((size_t)b * 66) * NN;
    }
    const int sb = s * 2 + b;
    const bf16* M = (ord ? adj2b : adjb) + ((size_t)sb << 20);
    const bf16* A = M + (size_t)(n0 + lr) * NN + lq * 8;
    const bf16* Xp = X + (size_t)lr * NN + lq * 8;

    f32x4 acc[2][4];
#pragma unroll
    for (int nt = 0; nt < 2; ++nt)
#pragma unroll
        for (int m = 0; m < 4; ++m) acc[nt][m] = (f32x4){0.f, 0.f, 0.f, 0.f};
    const int vbeg = wave * 256;
#pragma unroll 2
    for (int i = 0; i < 8; ++i) {
        const int v0 = vbeg + i * 32;
        short8 bfr[2], af[4];
#pragma unroll
        for (int nt = 0; nt < 2; ++nt)
            bfr[nt] = *reinterpret_cast<const short8*>(A + (size_t)nt * 16 * NN + v0);
#pragma unroll
        for (int m = 0; m < 4; ++m)
            af[m] = *reinterpret_cast<const short8*>(Xp + (size_t)m * 16 * NN + v0);
#pragma unroll
        for (int nt = 0; nt < 2; ++nt)
#pragma unroll
            for (int m = 0; m < 4; ++m)
                acc[nt][m] = __builtin_amdgcn_mfma_f32_16x16x32_bf16(af[m], bfr[nt], acc[nt][m], 0, 0, 0);
    }
    __shared__ f32x4 red[3][2][4][64];
    if (wave > 0) {
#pragma unroll
        for (int nt = 0; nt < 2; ++nt)
#pragma unroll
            for (int m = 0; m < 4; ++m) red[wave - 1][nt][m][lane] = acc[nt][m];
    }
    __syncthreads();
    if (wave == 0) {
#pragma unroll
        for (int nt = 0; nt < 2; ++nt) {
#pragma unroll
            for (int m = 0; m < 4; ++m)
                acc[nt][m] += red[0][nt][m][lane] + red[1][nt][m][lane] + red[2][nt][m][lane];
            const int p = b * NN + n0 + nt * 16 + lr;
            if (toGc) {
#pragma unroll
                for (int m = 0; m < 4; ++m)
                    *reinterpret_cast<f32x4*>(&gcT[(size_t)p * 128 + s * 64 + m * 16 + lq * 4]) = acc[nt][m];
            } else {
                bf16* dst = ((mode == 0) ? zT : zcT) + (size_t)p * ZS + 68 + (s * 2 + ord) * 68;
#pragma unroll
                for (int m = 0; m < 4; ++m) {
                    short4v o = { bf16s(acc[nt][m][0]), bf16s(acc[nt][m][1]),
                                  bf16s(acc[nt][m][2]), bf16s(acc[nt][m][3]) };
                    *reinterpret_cast<short4v*>(dst + m * 16 + lq * 4) = o;
                }
            }
        }
    }
}

// ---------------- dif2: diffuse x2,m (2 ch) -> both zT and zcT slots ----------------
__global__ __launch_bounds__(256) void k_dif2(
    const bf16* __restrict__ adjb, const bf16* __restrict__ adj2b,
    const bf16* __restrict__ zb, bf16* __restrict__ zT, bf16* __restrict__ zcT)
{
    const int i = blockIdx.y;
    const int b = i & 1, s = (i >> 1) & 1, ord = i >> 2;
    const int sb = s * 2 + b;
    const int wave = threadIdx.x >> 6, lane = threadIdx.x & 63;
    const int lr = lane & 15, lq = lane >> 4;
    const int n0 = blockIdx.x * 16;
    const bf16* M = (ord ? adj2b : adjb) + ((size_t)sb << 20);
    const bf16* A = M + (size_t)(n0 + lr) * NN + lq * 8;
    const bf16* Xp = zb + ((size_t)(b * 66 + 64) + lr) * NN + lq * 8;

    f32x4 acc = (f32x4){0.f, 0.f, 0.f, 0.f};
    const short8 zsh = {0, 0, 0, 0, 0, 0, 0, 0};
    const int vbeg = wave * 256;
#pragma unroll 4
    for (int i2 = 0; i2 < 8; ++i2) {
        const int v0 = vbeg + i2 * 32;
        short8 bfr = *reinterpret_cast<const short8*>(A + v0);
        short8 af = (lr < 2) ? *reinterpret_cast<const short8*>(Xp + v0) : zsh;
        acc = __builtin_amdgcn_mfma_f32_16x16x32_bf16(af, bfr, acc, 0, 0, 0);
    }
    __shared__ f32x4 red2[3][64];
    if (wave > 0) red2[wave - 1][lane] = acc;
    __syncthreads();
    if (wave == 0 && lq == 0) {
        acc += red2[0][lane] + red2[1][lane] + red2[2][lane];
        const int p = b * NN + n0 + lr;
        const size_t off = (size_t)p * ZS + 68 + (s * 2 + ord) * 68 + 64;
#pragma unroll
        for (int q = 0; q < 2; ++q) {
            const bf16 v = __float2bfloat16(acc[q]);
            zT[off + q] = v; zcT[off + q] = v;
        }
    }
}

// ---------------- stepB: dec2 + xs2 fused (wave-per-node) ----------------
__global__ __launch_bounds__(256) void k_stepB(
    const float* __restrict__ gcT, const float* __restrict__ hTf,
    const float* __restrict__ Wlout, const float* __restrict__ blout2,
    const float* __restrict__ prelu_a, const float* __restrict__ Wro,
    const float* __restrict__ bro, const float* __restrict__ x1b,
    const int* __restrict__ mask,
    float* __restrict__ imp, float* __restrict__ repr,
    bf16* __restrict__ zb, bf16* __restrict__ zcb,
    bf16* __restrict__ zT, bf16* __restrict__ zcT, int t)
{
    const int wv = threadIdx.x >> 6, lane = threadIdx.x & 63;
    const int p = blockIdx.x * 4 + wv;
    const int b = p >> 10, n = p & (NN - 1);
    __shared__ float gl[4][64], hl[4][64];
    const float g = gcT[(size_t)p * 128 + lane] + gcT[(size_t)p * 128 + 64 + lane];
    const float hv = hTf[(size_t)p * 64 + lane];
    gl[wv][lane] = g;
    hl[wv][lane] = hv;
    __syncthreads();
    const float* w = Wlout + (size_t)lane * 128;
    float a = 0.f;
#pragma unroll 8
    for (int j = 0; j < 64; ++j)
        a += w[j] * gl[wv][j] + w[64 + j] * hl[wv][j];
    float v = a + blout2[lane];
    v = (v >= 0.f) ? v : prelu_a[0] * v;
    repr[(((size_t)b * 128 + lane) * NN + n) * TT + t] = v;
    repr[(((size_t)b * 128 + 64 + lane) * NN + n) * TT + t] = hv;
    float s = Wro[lane] * v + Wro[64 + lane] * hv;
#pragma unroll
    for (int off = 32; off > 0; off >>= 1) s += __shfl_xor(s, off);
    if (lane == 0) {
        const float xs2 = s + bro[0];
        const size_t xi = (size_t)p * TT + t;
        imp[xi] = xs2;
        const int mi = mask[xi];
        const float x2 = mi ? x1b[p] : xs2;
        const bf16 x2b = __float2bfloat16(x2);
        const bf16 mb = __float2bfloat16((float)mi);
        zb[((size_t)b * 66 + 64) * NN + n] = x2b;
        zb[((size_t)b * 66 + 65) * NN + n] = mb;
        zcb[((size_t)b * 66 + 64) * NN + n] = x2b;
        zcb[((size_t)b * 66 + 65) * NN + n] = mb;
        zT[(size_t)p * ZS + 64] = x2b; zT[(size_t)p * ZS + 65] = mb;
        zcT[(size_t)p * ZS + 64] = x2b; zcT[(size_t)p * ZS + 65] = mb;
    }
}

// ---------------- gates: MFMA [Wr;Wu].zT + epilogue ----------------
__global__ __launch_bounds__(64) void k_gates(
    const bf16* __restrict__ Wrub, const bf16* __restrict__ zT,
    const float* __restrict__ br, const float* __restrict__ bu,
    const float* __restrict__ hTf,
    float* __restrict__ uT, bf16* __restrict__ zcb, bf16* __restrict__ zcT)
{
    const int lane = threadIdx.x & 63, lr = lane & 15, lq = lane >> 4;
    const int p = blockIdx.x * 16 + lr;
    const bf16* B = zT + (size_t)p * ZS;
    f32x4 acc[8];
#pragma unroll
    for (int m = 0; m < 8; ++m) acc[m] = (f32x4){0.f, 0.f, 0.f, 0.f};
#pragma unroll 2
    for (int ks = 0; ks < 11; ++ks) {
        short8 bfr = *reinterpret_cast<const short8*>(B + ks * 32 + lq * 8);
#pragma unroll
        for (int m = 0; m < 8; ++m) {
            short8 af = *reinterpret_cast<const short8*>(Wrub + (size_t)(m * 16 + lr) * ZS + ks * 32 + lq * 8);
            acc[m] = __builtin_amdgcn_mfma_f32_16x16x32_bf16(af, bfr, acc[m], 0, 0, 0);
        }
    }
    const int b = p >> 10, n = p & (NN - 1);
#pragma unroll
    for (int m = 0; m < 4; ++m) {
        f32x4 uq;
        short4v rq;
#pragma unroll
        for (int q = 0; q < 4; ++q) {
            const int oc = m * 16 + lq * 4 + q;
            const float rv = sigmoidf_(acc[m][q] + br[oc]);
            const float uv = sigmoidf_(acc[m + 4][q] + bu[oc]);
            const float hv = hTf[(size_t)p * 64 + oc];
            const float rh = rv * hv;
            uq[q] = uv;
            rq[q] = bf16s(rh);
            zcb[((size_t)b * 66 + oc) * NN + n] = __float2bfloat16(rh);
        }
        *reinterpret_cast<f32x4*>(&uT[(size_t)p * 64 + m * 16 + lq * 4]) = uq;
        *reinterpret_cast<short4v*>(&zcT[(size_t)p * ZS + m * 16 + lq * 4]) = rq;
    }
}

// ---------------- cellpre: cell (h update) + pre(t+1) fused via LDS transpose ----------------
__global__ __launch_bounds__(64) void k_cellpre(
    const bf16* __restrict__ Wcb, const bf16* __restrict__ zcT,
    const float* __restrict__ bc, const float* __restrict__ uT,
    float* __restrict__ hTf, bf16* __restrict__ zT, bf16* __restrict__ zb,
    const bf16* __restrict__ Wpre, const float* __restrict__ Wcomb,
    const float* __restrict__ bcomb, const float* __restrict__ bfsp,
    const float* __restrict__ x, const int* __restrict__ mask,
    bf16* __restrict__ yb, float* __restrict__ x1b, float* __restrict__ pred, int tn)
{
    const int lane = threadIdx.x & 63, lr = lane & 15, lq = lane >> 4;
    const int p = blockIdx.x * 16 + lr;
    const int b = p >> 10, n = p & (NN - 1);
    __shared__ short hsm[16][72];   // [node][oc] bf16

    // ---- cell ----
    {
        const bf16* B = zcT + (size_t)p * ZS;
        f32x4 acc[4];
#pragma unroll
        for (int m = 0; m < 4; ++m) acc[m] = (f32x4){0.f, 0.f, 0.f, 0.f};
#pragma unroll 2
        for (int ks = 0; ks < 11; ++ks) {
            short8 bfr = *reinterpret_cast<const short8*>(B + ks * 32 + lq * 8);
#pragma unroll
            for (int m = 0; m < 4; ++m) {
                short8 af = *reinterpret_cast<const short8*>(Wcb + (size_t)(m * 16 + lr) * ZS + ks * 32 + lq * 8);
                acc[m] = __builtin_amdgcn_mfma_f32_16x16x32_bf16(af, bfr, acc[m], 0, 0, 0);
            }
        }
#pragma unroll
        for (int m = 0; m < 4; ++m) {
            f32x4 hq;
            short4v hb;
#pragma unroll
            for (int q = 0; q < 4; ++q) {
                const int oc = m * 16 + lq * 4 + q;
                const float cv = tanhf(acc[m][q] + bc[oc]);
                const float uv = uT[(size_t)p * 64 + oc];
                const float ho = hTf[(size_t)p * 64 + oc];
                const float hn = uv * ho + (1.f - uv) * cv;
                hq[q] = hn;
                hb[q] = bf16s(hn);
                hsm[lr][oc] = hb[q];
                zb[((size_t)b * 66 + oc) * NN + n] = __float2bfloat16(hn);
            }
            *reinterpret_cast<f32x4*>(&hTf[(size_t)p * 64 + m * 16 + lq * 4]) = hq;
            *reinterpret_cast<short4v*>(&zT[(size_t)p * ZS + m * 16 + lq * 4]) = hb;
        }
    }
    __syncthreads();

    // ---- pre(tn): B-frags from LDS h ----
    {
        f32x4 acc[9];
#pragma unroll
        for (int m = 0; m < 9; ++m) acc[m] = (f32x4){0.f, 0.f, 0.f, 0.f};
#pragma unroll
        for (int ks = 0; ks < 2; ++ks) {
            short8 bfr = *reinterpret_cast<const short8*>(&hsm[lr][ks * 32 + lq * 8]);
#pragma unroll
            for (int m = 0; m < 9; ++m) {
                short8 af = *reinterpret_cast<const short8*>(Wpre + (size_t)(m * 16 + lr) * 64 + ks * 32 + lq * 8);
                acc[m] = __builtin_amdgcn_mfma_f32_16x16x32_bf16(af, bfr, acc[m], 0, 0, 0);
            }
        }
        const size_t xi = (size_t)p * TT + tn;
        const float xs1v = acc[0][0] + bfsp[0];
        const float xs1 = __shfl(xs1v, lr);
        const int mi = mask[xi];
        const float mf = (float)mi;
        const float x1 = mi ? x[xi] : xs1;
        if (lq == 0) { pred[xi] = xs1; x1b[p] = x1; }
#pragma unroll
        for (int m = 0; m < 9; ++m)
#pragma unroll
            for (int q = 0; q < 4; ++q) {
                const int o = m * 16 + lq * 4 + q - 1;
                if (o >= 0 && o < 128) {
                    const float val = acc[m][q] + Wcomb[o * 66] * x1 + Wcomb[o * 66 + 1] * mf + bcomb[o];
                    yb[(size_t)(b * 128 + o) * NN + n] = __float2bfloat16(val);
                }
            }
    }
}

extern "C" void kernel_launch(void* const* d_in, const int* in_sizes, int n_in,
                              void* d_out, int out_size, void* d_ws, size_t ws_size,
                              hipStream_t stream)
{
    const float* x     = (const float*)d_in[0];
    const int*   mask  = (const int*)  d_in[1];
    const float* adj   = (const float*)d_in[2];
    const float* Wr    = (const float*)d_in[3];
    const float* br    = (const float*)d_in[4];
    const float* Wu    = (const float*)d_in[5];
    const float* bu    = (const float*)d_in[6];
    const float* Wc    = (const float*)d_in[7];
    const float* bc    = (const float*)d_in[8];
    const float* Wfs   = (const float*)d_in[9];
    const float* bfs   = (const float*)d_in[10];
    const float* Wdin  = (const float*)d_in[11];
    const float* bdin  = (const float*)d_in[12];
    const float* Wgc   = (const float*)d_in[13];
    const float* bgc   = (const float*)d_in[14];
    const float* Wlout = (const float*)d_in[15];
    const float* blout = (const float*)d_in[16];
    const float* Wro   = (const float*)d_in[17];
    const float* bro   = (const float*)d_in[18];
    const float* pa    = (const float*)d_in[19];

    float* ws = (float*)d_ws;
    float* Wcomb  = ws + 0;          // 8448
    float* bcomb  = ws + 8448;       // 128
    float* blout2 = ws + 8576;       // 64
    float* x1b    = ws + 8640;       // 2048
    float* gcT    = ws + 10688;      // 262144
    float* uT     = ws + 272832;     // 131072
    float* hTf    = ws + 403904;     // 131072   <- memset region start
    bf16* bfp   = (bf16*)(ws + 534976);
    bf16* zb    = bfp + 0;           // 135168
    bf16* zcb   = bfp + 135168;      // 135168
    bf16* zT    = bfp + 270336;      // 720896
    bf16* zcT   = bfp + 991232;      // 720896   <- memset region end (bfp+1712128)
    bf16* adjb  = bfp + 1712128;     // 4194304
    bf16* adjtb = bfp + 5906432;     // 4194304
    bf16* adj2b = bfp + 10100736;    // 4194304
    bf16* yb    = bfp + 14295040;    // 262144
    bf16* Wpre  = bfp + 14557184;    // 9216
    bf16* Wrub  = bfp + 14566400;    // 45056
    bf16* Wcb   = bfp + 14611456;    // 22528

    float* imp  = (float*)d_out;
    float* pred = imp + (size_t)BB * NN * TT;
    float* repr = imp + (size_t)2 * BB * NN * TT;

    hipMemsetAsync(hTf, 0, 131072 * 4 + (size_t)1712128 * 2, stream);
    hipLaunchKernelGGL(k_prep, dim3(334), dim3(256), 0, stream,
                       Wgc, bgc, Wdin, bdin, Wlout, blout, Wfs, Wr, Wu, Wc,
                       Wcomb, bcomb, blout2, Wpre, Wrub, Wcb);
    hipLaunchKernelGGL(k_cvtT, dim3(16, 16, 4), dim3(256), 0, stream, adj, adjb, adjtb);
    hipLaunchKernelGGL(k_a2, dim3(8, 16, 4), dim3(256), 0, stream, adjb, adjtb, adj2b);

    hipLaunchKernelGGL(k_pre, dim3(128), dim3(64), 0, stream,
                       Wpre, zT, Wcomb, bcomb, bfs, x, mask, yb, x1b, pred, 0);

    for (int t = 0; t < TT; ++t) {
        const int ncombo = (t < TT - 1) ? 12 : 4;
        hipLaunchKernelGGL(k_difN, dim3(32, ncombo), dim3(256), 0, stream,
                           0, adjb, adj2b, yb, zb, zcb, gcT, zT, zcT);
        hipLaunchKernelGGL(k_stepB, dim3(512), dim3(256), 0, stream,
                           gcT, hTf, Wlout, blout2, pa, Wro, bro, x1b, mask,
                           imp, repr, zb, zcb, zT, zcT, t);
        if (t < TT - 1) {
            hipLaunchKernelGGL(k_dif2, dim3(64, 8), dim3(256), 0, stream,
                               adjb, adj2b, zb, zT, zcT);
            hipLaunchKernelGGL(k_gates, dim3(128), dim3(64), 0, stream,
                               Wrub, zT, br, bu, hTf, uT, zcb, zcT);
            hipLaunchKernelGGL(k_difN, dim3(32, 8), dim3(256), 0, stream,
                               1, adjb, adj2b, yb, zb, zcb, gcT, zT, zcT);
            hipLaunchKernelGGL(k_cellpre, dim3(128), dim3(64), 0, stream,
                               Wcb, zcT, bc, uT, hTf, zT, zb,
                               Wpre, Wcomb, bcomb, bfs, x, mask, yb, x1b, pred, t + 1);
        }
    }
}

// Round 9
// 765.156 us; speedup vs baseline: 8.3271x; 1.0039x over previous
//
#include <hip/hip_runtime.h>
#include <hip/hip_bf16.h>
#include <cstddef>

#define NN 1024
#define BB 2
#define TT 12
#define ZS 352   // zT/zcT row stride: [h(0..63), x2(64), m(65), pad, 4 slots @68: [hdiff(0..63), x2d(64), md(65), pad]]

typedef __attribute__((ext_vector_type(8))) short short8;
typedef __attribute__((ext_vector_type(4))) short short4v;
typedef __attribute__((ext_vector_type(4))) float f32x4;
typedef __hip_bfloat16 bf16;

__device__ __forceinline__ float sigmoidf_(float v) { return 1.0f / (1.0f + expf(-v)); }
__device__ __forceinline__ short bf16s(float f) { bf16 h = __float2bfloat16(f); return *reinterpret_cast<short*>(&h); }

// ---------------- one-time weight prep ----------------
__device__ __forceinline__ float mapcol(const float* src, int c) {
    if (c < 64) return src[2 + c];
    if (c == 64) return src[0];
    if (c == 65) return src[1];
    if (c < 68 || c >= 340) return 0.f;
    const int d = c - 68, bk = d / 68, off = d % 68;
    if (off < 64) return src[66 + bk * 66 + 2 + off];
    if (off == 64) return src[66 + bk * 66];
    if (off == 65) return src[66 + bk * 66 + 1];
    return 0.f;
}

__global__ __launch_bounds__(256) void k_prep(
    const float* __restrict__ Wgc, const float* __restrict__ bgc,
    const float* __restrict__ Wdin, const float* __restrict__ bdin,
    const float* __restrict__ Wlout, const float* __restrict__ blout,
    const float* __restrict__ Wfs,
    const float* __restrict__ Wr, const float* __restrict__ Wu, const float* __restrict__ Wc,
    float* __restrict__ Wcomb, float* __restrict__ bcomb, float* __restrict__ blout2,
    bf16* __restrict__ Wpre, bf16* __restrict__ Wrub, bf16* __restrict__ Wcb)
{
    const int idx = blockIdx.x * 256 + threadIdx.x;
    if (idx < 8448) {
        const int o = idx / 66, k = idx % 66;
        const float* g = Wgc + (size_t)(o & 63) * 128 + (o >> 6) * 64;
        float a = 0.f;
#pragma unroll 8
        for (int c = 0; c < 64; ++c) a += g[c] * Wdin[c * 66 + k];
        Wcomb[idx] = a;
    } else if (idx < 8576) {
        const int o = idx - 8448;
        const float* g = Wgc + (size_t)(o & 63) * 128 + (o >> 6) * 64;
        float a = 0.f;
#pragma unroll 8
        for (int c = 0; c < 64; ++c) a += g[c] * bdin[c];
        bcomb[o] = a;
    } else if (idx < 8640) {
        const int oc = idx - 8576;
        float a = blout[oc];
#pragma unroll 8
        for (int j = 0; j < 64; ++j) a += Wlout[(size_t)oc * 128 + j] * bgc[j];
        blout2[oc] = a;
    } else if (idx < 17856) {
        const int j = idx - 8640, r = j >> 6, k = j & 63;
        float v = 0.f;
        if (r == 0) v = Wfs[k];
        else if (r <= 128) {
            const int o = r - 1;
            const float* g = Wgc + (size_t)(o & 63) * 128 + (o >> 6) * 64;
#pragma unroll 8
            for (int c = 0; c < 64; ++c) v += g[c] * Wdin[c * 66 + 2 + k];
        }
        Wpre[j] = __float2bfloat16(v);
    } else if (idx < 62912) {
        const int j = idx - 17856, r = j / 352, c = j % 352;
        const float* src = (r < 64) ? (Wr + (size_t)r * 330) : (Wu + (size_t)(r - 64) * 330);
        Wrub[j] = __float2bfloat16(mapcol(src, c));
    } else if (idx < 85440) {
        const int j = idx - 62912, r = j / 352, c = j % 352;
        Wcb[j] = __float2bfloat16(mapcol(Wc + (size_t)r * 330, c));
    }
}

// ---------------- adj fp32 -> bf16 (adjb) + transposed (adjtb) ----------------
__global__ __launch_bounds__(256) void k_cvtT(const float* __restrict__ adj,
                                              bf16* __restrict__ adjb, bf16* __restrict__ adjtb)
{
    const int sb = blockIdx.z;
    const int r0 = blockIdx.y * 64, c0 = blockIdx.x * 64;
    const float* A = adj + ((size_t)sb << 20);
    __shared__ short tile[64][72];
    const int tr = threadIdx.x >> 4, tc = (threadIdx.x & 15) * 4;
#pragma unroll
    for (int i = 0; i < 4; ++i) {
        const int r = tr + i * 16;
        float4 v = *reinterpret_cast<const float4*>(&A[(size_t)(r0 + r) * NN + c0 + tc]);
        short4v o = { bf16s(v.x), bf16s(v.y), bf16s(v.z), bf16s(v.w) };
        *reinterpret_cast<short4v*>(&adjb[((size_t)sb << 20) + (size_t)(r0 + r) * NN + c0 + tc]) = o;
        tile[r][tc + 0] = o.x; tile[r][tc + 1] = o.y; tile[r][tc + 2] = o.z; tile[r][tc + 3] = o.w;
    }
    __syncthreads();
#pragma unroll
    for (int i = 0; i < 4; ++i) {
        const int v = tr + i * 16;
        short4v o = { tile[tc + 0][v], tile[tc + 1][v], tile[tc + 2][v], tile[tc + 3][v] };
        *reinterpret_cast<short4v*>(&adjtb[((size_t)sb << 20) + (size_t)(c0 + v) * NN + r0 + tc]) = o;
    }
}

// ---------------- A^2: TLP version. 64w x 16v per wave, grid (16,16,4) = 1024 blocks ----------------
// adj2b[sb][w][v] = sum_k adjb[sb][w][k] * adjtb[sb][v][k]
__global__ __launch_bounds__(256) void k_a2(const bf16* __restrict__ adjb,
                                            const bf16* __restrict__ adjtb,
                                            bf16* __restrict__ adj2b)
{
    const int sb = blockIdx.z;
    const int wave = threadIdx.x >> 6, lane = threadIdx.x & 63;
    const int lr = lane & 15, lq = lane >> 4;
    const int v0 = blockIdx.x * 64 + wave * 16;
    const int w0 = blockIdx.y * 64;
    const bf16* AT = adjtb + ((size_t)sb << 20) + (size_t)(v0 + lr) * NN + lq * 8;
    const bf16* Ar = adjb + ((size_t)sb << 20) + (size_t)(w0 + lr) * NN + lq * 8;
    f32x4 acc[4];
#pragma unroll
    for (int m = 0; m < 4; ++m) acc[m] = (f32x4){0.f, 0.f, 0.f, 0.f};
#pragma unroll 4
    for (int k0 = 0; k0 < NN; k0 += 32) {
        short8 bfr = *reinterpret_cast<const short8*>(AT + k0);
        short8 af[4];
#pragma unroll
        for (int m = 0; m < 4; ++m)
            af[m] = *reinterpret_cast<const short8*>(Ar + (size_t)m * 16 * NN + k0);
#pragma unroll
        for (int m = 0; m < 4; ++m)
            acc[m] = __builtin_amdgcn_mfma_f32_16x16x32_bf16(af[m], bfr, acc[m], 0, 0, 0);
    }
    bf16* D = adj2b + ((size_t)sb << 20);
#pragma unroll
    for (int m = 0; m < 4; ++m)
#pragma unroll
        for (int q = 0; q < 4; ++q)
            D[(size_t)(w0 + m * 16 + lq * 4 + q) * NN + v0 + lr] = __float2bfloat16(acc[m][q]);
}

// ---------------- pre (standalone, t=0): MFMA [Wfs;Wcomb_h].h + epilogue ----------------
__global__ __launch_bounds__(64) void k_pre(
    const bf16* __restrict__ Wpre, const bf16* __restrict__ zT,
    const float* __restrict__ Wcomb, const float* __restrict__ bcomb,
    const float* __restrict__ bfsp,
    const float* __restrict__ x, const int* __restrict__ mask,
    bf16* __restrict__ yb, float* __restrict__ x1b, float* __restrict__ pred, int t)
{
    const int lane = threadIdx.x & 63, lr = lane & 15, lq = lane >> 4;
    const int p = blockIdx.x * 16 + lr;
    const bf16* B = zT + (size_t)p * ZS;
    f32x4 acc[9];
#pragma unroll
    for (int m = 0; m < 9; ++m) acc[m] = (f32x4){0.f, 0.f, 0.f, 0.f};
#pragma unroll
    for (int ks = 0; ks < 2; ++ks) {
        short8 bfr = *reinterpret_cast<const short8*>(B + ks * 32 + lq * 8);
#pragma unroll
        for (int m = 0; m < 9; ++m) {
            short8 af = *reinterpret_cast<const short8*>(Wpre + (size_t)(m * 16 + lr) * 64 + ks * 32 + lq * 8);
            acc[m] = __builtin_amdgcn_mfma_f32_16x16x32_bf16(af, bfr, acc[m], 0, 0, 0);
        }
    }
    const int b = p >> 10, n = p & (NN - 1);
    const size_t xi = (size_t)p * TT + t;
    const float xs1v = acc[0][0] + bfsp[0];
    const float xs1 = __shfl(xs1v, lr);
    const int mi = mask[xi];
    const float mf = (float)mi;
    const float x1 = mi ? x[xi] : xs1;
    if (lq == 0) { pred[xi] = xs1; x1b[p] = x1; }
#pragma unroll
    for (int m = 0; m < 9; ++m)
#pragma unroll
        for (int q = 0; q < 4; ++q) {
            const int o = m * 16 + lq * 4 + q - 1;
            if (o >= 0 && o < 128) {
                const float val = acc[m][q] + Wcomb[o * 66] * x1 + Wcomb[o * 66 + 1] * mf + bcomb[o];
                yb[(size_t)(b * 128 + o) * NN + n] = __float2bfloat16(val);
            }
        }
}

// ---------------- diffusion: 2 n-tiles/wave, split-K 4 waves ----------------
__global__ __launch_bounds__(256) void k_difN(
    int mode, const bf16* __restrict__ adjb, const bf16* __restrict__ adj2b,
    const bf16* __restrict__ yb, const bf16* __restrict__ zb, const bf16* __restrict__ zcb,
    float* __restrict__ gcT, bf16* __restrict__ zT, bf16* __restrict__ zcT)
{
    const int combo = blockIdx.y;
    const int wave = threadIdx.x >> 6, lane = threadIdx.x & 63;
    const int lr = lane & 15, lq = lane >> 4;
    const int n0 = blockIdx.x * 32;

    int s, b, ord; const bf16* X; bool toGc = false;
    if (mode == 0 && combo < 4) {
        s = combo >> 1; b = combo & 1; ord = 0; toGc = true;
        X = yb + ((size_t)(b * 128 + s * 64)) * NN;
    } else {
        const int i = (mode == 0) ? combo - 4 : combo;
        b = i & 1; s = (i >> 1) & 1; ord = i >> 2;
        X = ((mode == 0) ? zb : zcb) + ((size_t)b * 66) * NN;
    }
    const int sb = s * 2 + b;
    const bf16* M = (ord ? adj2b : adjb) + ((size_t)sb << 20);
    const bf16* A = M + (size_t)(n0 + lr) * NN + lq * 8;
    const bf16* Xp = X + (size_t)lr * NN + lq * 8;

    f32x4 acc[2][4];
#pragma unroll
    for (int nt = 0; nt < 2; ++nt)
#pragma unroll
        for (int m = 0; m < 4; ++m) acc[nt][m] = (f32x4){0.f, 0.f, 0.f, 0.f};
    const int vbeg = wave * 256;
#pragma unroll 2
    for (int i = 0; i < 8; ++i) {
        const int v0 = vbeg + i * 32;
        short8 bfr[2], af[4];
#pragma unroll
        for (int nt = 0; nt < 2; ++nt)
            bfr[nt] = *reinterpret_cast<const short8*>(A + (size_t)nt * 16 * NN + v0);
#pragma unroll
        for (int m = 0; m < 4; ++m)
            af[m] = *reinterpret_cast<const short8*>(Xp + (size_t)m * 16 * NN + v0);
#pragma unroll
        for (int nt = 0; nt < 2; ++nt)
#pragma unroll
            for (int m = 0; m < 4; ++m)
                acc[nt][m] = __builtin_amdgcn_mfma_f32_16x16x32_bf16(af[m], bfr[nt], acc[nt][m], 0, 0, 0);
    }
    __shared__ f32x4 red[3][2][4][64];
    if (wave > 0) {
#pragma unroll
        for (int nt = 0; nt < 2; ++nt)
#pragma unroll
            for (int m = 0; m < 4; ++m) red[wave - 1][nt][m][lane] = acc[nt][m];
    }
    __syncthreads();
    if (wave == 0) {
#pragma unroll
        for (int nt = 0; nt < 2; ++nt) {
#pragma unroll
            for (int m = 0; m < 4; ++m)
                acc[nt][m] += red[0][nt][m][lane] + red[1][nt][m][lane] + red[2][nt][m][lane];
            const int p = b * NN + n0 + nt * 16 + lr;
            if (toGc) {
#pragma unroll
                for (int m = 0; m < 4; ++m)
                    *reinterpret_cast<f32x4*>(&gcT[(size_t)p * 128 + s * 64 + m * 16 + lq * 4]) = acc[nt][m];
            } else {
                bf16* dst = ((mode == 0) ? zT : zcT) + (size_t)p * ZS + 68 + (s * 2 + ord) * 68;
#pragma unroll
                for (int m = 0; m < 4; ++m) {
                    short4v o = { bf16s(acc[nt][m][0]), bf16s(acc[nt][m][1]),
                                  bf16s(acc[nt][m][2]), bf16s(acc[nt][m][3]) };
                    *reinterpret_cast<short4v*>(dst + m * 16 + lq * 4) = o;
                }
            }
        }
    }
}

// ---------------- dif2: diffuse x2,m (2 ch) -> both zT and zcT slots ----------------
__global__ __launch_bounds__(256) void k_dif2(
    const bf16* __restrict__ adjb, const bf16* __restrict__ adj2b,
    const bf16* __restrict__ zb, bf16* __restrict__ zT, bf16* __restrict__ zcT)
{
    const int i = blockIdx.y;
    const int b = i & 1, s = (i >> 1) & 1, ord = i >> 2;
    const int sb = s * 2 + b;
    const int wave = threadIdx.x >> 6, lane = threadIdx.x & 63;
    const int lr = lane & 15, lq = lane >> 4;
    const int n0 = blockIdx.x * 16;
    const bf16* M = (ord ? adj2b : adjb) + ((size_t)sb << 20);
    const bf16* A = M + (size_t)(n0 + lr) * NN + lq * 8;
    const bf16* Xp = zb + ((size_t)(b * 66 + 64) + lr) * NN + lq * 8;

    f32x4 acc = (f32x4){0.f, 0.f, 0.f, 0.f};
    const short8 zsh = {0, 0, 0, 0, 0, 0, 0, 0};
    const int vbeg = wave * 256;
#pragma unroll 4
    for (int i2 = 0; i2 < 8; ++i2) {
        const int v0 = vbeg + i2 * 32;
        short8 bfr = *reinterpret_cast<const short8*>(A + v0);
        short8 af = (lr < 2) ? *reinterpret_cast<const short8*>(Xp + v0) : zsh;
        acc = __builtin_amdgcn_mfma_f32_16x16x32_bf16(af, bfr, acc, 0, 0, 0);
    }
    __shared__ f32x4 red2[3][64];
    if (wave > 0) red2[wave - 1][lane] = acc;
    __syncthreads();
    if (wave == 0 && lq == 0) {
        acc += red2[0][lane] + red2[1][lane] + red2[2][lane];
        const int p = b * NN + n0 + lr;
        const size_t off = (size_t)p * ZS + 68 + (s * 2 + ord) * 68 + 64;
#pragma unroll
        for (int q = 0; q < 2; ++q) {
            const bf16 v = __float2bfloat16(acc[q]);
            zT[off + q] = v; zcT[off + q] = v;
        }
    }
}

// ---------------- stepB: dec2 + xs2 fused (wave-per-node) ----------------
__global__ __launch_bounds__(256) void k_stepB(
    const float* __restrict__ gcT, const float* __restrict__ hTf,
    const float* __restrict__ Wlout, const float* __restrict__ blout2,
    const float* __restrict__ prelu_a, const float* __restrict__ Wro,
    const float* __restrict__ bro, const float* __restrict__ x1b,
    const int* __restrict__ mask,
    float* __restrict__ imp, float* __restrict__ repr,
    bf16* __restrict__ zb, bf16* __restrict__ zcb,
    bf16* __restrict__ zT, bf16* __restrict__ zcT, int t)
{
    const int wv = threadIdx.x >> 6, lane = threadIdx.x & 63;
    const int p = blockIdx.x * 4 + wv;
    const int b = p >> 10, n = p & (NN - 1);
    __shared__ float gl[4][64], hl[4][64];
    const float g = gcT[(size_t)p * 128 + lane] + gcT[(size_t)p * 128 + 64 + lane];
    const float hv = hTf[(size_t)p * 64 + lane];
    gl[wv][lane] = g;
    hl[wv][lane] = hv;
    __syncthreads();
    const float* w = Wlout + (size_t)lane * 128;
    float a = 0.f;
#pragma unroll 8
    for (int j = 0; j < 64; ++j)
        a += w[j] * gl[wv][j] + w[64 + j] * hl[wv][j];
    float v = a + blout2[lane];
    v = (v >= 0.f) ? v : prelu_a[0] * v;
    repr[(((size_t)b * 128 + lane) * NN + n) * TT + t] = v;
    repr[(((size_t)b * 128 + 64 + lane) * NN + n) * TT + t] = hv;
    float s = Wro[lane] * v + Wro[64 + lane] * hv;
#pragma unroll
    for (int off = 32; off > 0; off >>= 1) s += __shfl_xor(s, off);
    if (lane == 0) {
        const float xs2 = s + bro[0];
        const size_t xi = (size_t)p * TT + t;
        imp[xi] = xs2;
        const int mi = mask[xi];
        const float x2 = mi ? x1b[p] : xs2;
        const bf16 x2b = __float2bfloat16(x2);
        const bf16 mb = __float2bfloat16((float)mi);
        zb[((size_t)b * 66 + 64) * NN + n] = x2b;
        zb[((size_t)b * 66 + 65) * NN + n] = mb;
        zcb[((size_t)b * 66 + 64) * NN + n] = x2b;
        zcb[((size_t)b * 66 + 65) * NN + n] = mb;
        zT[(size_t)p * ZS + 64] = x2b; zT[(size_t)p * ZS + 65] = mb;
        zcT[(size_t)p * ZS + 64] = x2b; zcT[(size_t)p * ZS + 65] = mb;
    }
}

// ---------------- gates: 2-wave m-split MFMA [Wr;Wu].zT + epilogue ----------------
// wave 0 -> r rows (0..63), wave 1 -> u rows (64..127)
__global__ __launch_bounds__(128) void k_gates(
    const bf16* __restrict__ Wrub, const bf16* __restrict__ zT,
    const float* __restrict__ br, const float* __restrict__ bu,
    const float* __restrict__ hTf,
    float* __restrict__ uT, bf16* __restrict__ zcb, bf16* __restrict__ zcT)
{
    const int wave = threadIdx.x >> 6, lane = threadIdx.x & 63;
    const int lr = lane & 15, lq = lane >> 4;
    const int p = blockIdx.x * 16 + lr;
    const bf16* B = zT + (size_t)p * ZS;
    const bf16* WA = Wrub + (size_t)wave * 64 * ZS;
    f32x4 acc[4];
#pragma unroll
    for (int m = 0; m < 4; ++m) acc[m] = (f32x4){0.f, 0.f, 0.f, 0.f};
#pragma unroll 2
    for (int ks = 0; ks < 11; ++ks) {
        short8 bfr = *reinterpret_cast<const short8*>(B + ks * 32 + lq * 8);
#pragma unroll
        for (int m = 0; m < 4; ++m) {
            short8 af = *reinterpret_cast<const short8*>(WA + (size_t)(m * 16 + lr) * ZS + ks * 32 + lq * 8);
            acc[m] = __builtin_amdgcn_mfma_f32_16x16x32_bf16(af, bfr, acc[m], 0, 0, 0);
        }
    }
    const int b = p >> 10, n = p & (NN - 1);
    if (wave == 0) {
#pragma unroll
        for (int m = 0; m < 4; ++m) {
            short4v rq;
#pragma unroll
            for (int q = 0; q < 4; ++q) {
                const int oc = m * 16 + lq * 4 + q;
                const float rv = sigmoidf_(acc[m][q] + br[oc]);
                const float rh = rv * hTf[(size_t)p * 64 + oc];
                rq[q] = bf16s(rh);
                zcb[((size_t)b * 66 + oc) * NN + n] = __float2bfloat16(rh);
            }
            *reinterpret_cast<short4v*>(&zcT[(size_t)p * ZS + m * 16 + lq * 4]) = rq;
        }
    } else {
#pragma unroll
        for (int m = 0; m < 4; ++m) {
            f32x4 uq;
#pragma unroll
            for (int q = 0; q < 4; ++q) {
                const int oc = m * 16 + lq * 4 + q;
                uq[q] = sigmoidf_(acc[m][q] + bu[oc]);
            }
            *reinterpret_cast<f32x4*>(&uT[(size_t)p * 64 + m * 16 + lq * 4]) = uq;
        }
    }
}

// ---------------- cellpre: 2-wave m-split cell + pre(t+1) via LDS transpose ----------------
__global__ __launch_bounds__(128) void k_cellpre(
    const bf16* __restrict__ Wcb, const bf16* __restrict__ zcT,
    const float* __restrict__ bc, const float* __restrict__ uT,
    float* __restrict__ hTf, bf16* __restrict__ zT, bf16* __restrict__ zb,
    const bf16* __restrict__ Wpre, const float* __restrict__ Wcomb,
    const float* __restrict__ bcomb, const float* __restrict__ bfsp,
    const float* __restrict__ x, const int* __restrict__ mask,
    bf16* __restrict__ yb, float* __restrict__ x1b, float* __restrict__ pred, int tn)
{
    const int wave = threadIdx.x >> 6, lane = threadIdx.x & 63;
    const int lr = lane & 15, lq = lane >> 4;
    const int p = blockIdx.x * 16 + lr;
    const int b = p >> 10, n = p & (NN - 1);
    __shared__ short hsm[16][72];
    __shared__ float xs1s[16];

    // ---- cell: wave handles m-tiles {wave*2, wave*2+1} ----
    {
        const bf16* B = zcT + (size_t)p * ZS;
        f32x4 acc[2];
#pragma unroll
        for (int mm = 0; mm < 2; ++mm) acc[mm] = (f32x4){0.f, 0.f, 0.f, 0.f};
#pragma unroll 2
        for (int ks = 0; ks < 11; ++ks) {
            short8 bfr = *reinterpret_cast<const short8*>(B + ks * 32 + lq * 8);
#pragma unroll
            for (int mm = 0; mm < 2; ++mm) {
                const int m = wave * 2 + mm;
                short8 af = *reinterpret_cast<const short8*>(Wcb + (size_t)(m * 16 + lr) * ZS + ks * 32 + lq * 8);
                acc[mm] = __builtin_amdgcn_mfma_f32_16x16x32_bf16(af, bfr, acc[mm], 0, 0, 0);
            }
        }
#pragma unroll
        for (int mm = 0; mm < 2; ++mm) {
            const int m = wave * 2 + mm;
            f32x4 hq;
            short4v hb;
#pragma unroll
            for (int q = 0; q < 4; ++q) {
                const int oc = m * 16 + lq * 4 + q;
                const float cv = tanhf(acc[mm][q] + bc[oc]);
                const float uv = uT[(size_t)p * 64 + oc];
                const float ho = hTf[(size_t)p * 64 + oc];
                const float hn = uv * ho + (1.f - uv) * cv;
                hq[q] = hn;
                hb[q] = bf16s(hn);
                zb[((size_t)b * 66 + oc) * NN + n] = __float2bfloat16(hn);
            }
            *reinterpret_cast<f32x4*>(&hTf[(size_t)p * 64 + m * 16 + lq * 4]) = hq;
            *reinterpret_cast<short4v*>(&zT[(size_t)p * ZS + m * 16 + lq * 4]) = hb;
            *reinterpret_cast<short4v*>(&hsm[lr][m * 16 + lq * 4]) = hb;
        }
    }
    __syncthreads();

    // ---- pre(tn): wave0 m-tiles 0..4, wave1 m-tiles 5..8 ----
    {
        const int MB = wave ? 4 : 5;
        f32x4 acc[5];
#pragma unroll
        for (int m = 0; m < 5; ++m) acc[m] = (f32x4){0.f, 0.f, 0.f, 0.f};
#pragma unroll
        for (int ks = 0; ks < 2; ++ks) {
            short8 bfr = *reinterpret_cast<const short8*>(&hsm[lr][ks * 32 + lq * 8]);
#pragma unroll
            for (int m = 0; m < 5; ++m) {
                if (m < MB) {
                    const int mm = wave ? 5 + m : m;
                    short8 af = *reinterpret_cast<const short8*>(Wpre + (size_t)(mm * 16 + lr) * 64 + ks * 32 + lq * 8);
                    acc[m] = __builtin_amdgcn_mfma_f32_16x16x32_bf16(af, bfr, acc[m], 0, 0, 0);
                }
            }
        }
        if (wave == 0 && lq == 0) xs1s[lr] = acc[0][0] + bfsp[0];
        __syncthreads();
        const float xs1 = xs1s[lr];
        const size_t xi = (size_t)p * TT + tn;
        const int mi = mask[xi];
        const float mf = (float)mi;
        const float x1 = mi ? x[xi] : xs1;
        if (wave == 0 && lq == 0) { pred[xi] = xs1; x1b[p] = x1; }
#pragma unroll
        for (int m = 0; m < 5; ++m) {
            if (m < MB) {
                const int mm = wave ? 5 + m : m;
#pragma unroll
                for (int q = 0; q < 4; ++q) {
                    const int o = mm * 16 + lq * 4 + q - 1;
                    if (o >= 0 && o < 128) {
                        const float val = acc[m][q] + Wcomb[o * 66] * x1 + Wcomb[o * 66 + 1] * mf + bcomb[o];
                        yb[(size_t)(b * 128 + o) * NN + n] = __float2bfloat16(val);
                    }
                }
            }
        }
    }
}

extern "C" void kernel_launch(void* const* d_in, const int* in_sizes, int n_in,
                              void* d_out, int out_size, void* d_ws, size_t ws_size,
                              hipStream_t stream)
{
    const float* x     = (const float*)d_in[0];
    const int*   mask  = (const int*)  d_in[1];
    const float* adj   = (const float*)d_in[2];
    const float* Wr    = (const float*)d_in[3];
    const float* br    = (const float*)d_in[4];
    const float* Wu    = (const float*)d_in[5];
    const float* bu    = (const float*)d_in[6];
    const float* Wc    = (const float*)d_in[7];
    const float* bc    = (const float*)d_in[8];
    const float* Wfs   = (const float*)d_in[9];
    const float* bfs   = (const float*)d_in[10];
    const float* Wdin  = (const float*)d_in[11];
    const float* bdin  = (const float*)d_in[12];
    const float* Wgc   = (const float*)d_in[13];
    const float* bgc   = (const float*)d_in[14];
    const float* Wlout = (const float*)d_in[15];
    const float* blout = (const float*)d_in[16];
    const float* Wro   = (const float*)d_in[17];
    const float* bro   = (const float*)d_in[18];
    const float* pa    = (const float*)d_in[19];

    float* ws = (float*)d_ws;
    float* Wcomb  = ws + 0;          // 8448
    float* bcomb  = ws + 8448;       // 128
    float* blout2 = ws + 8576;       // 64
    float* x1b    = ws + 8640;       // 2048
    float* gcT    = ws + 10688;      // 262144
    float* uT     = ws + 272832;     // 131072
    float* hTf    = ws + 403904;     // 131072   <- memset region start
    bf16* bfp   = (bf16*)(ws + 534976);
    bf16* zb    = bfp + 0;           // 135168
    bf16* zcb   = bfp + 135168;      // 135168
    bf16* zT    = bfp + 270336;      // 720896
    bf16* zcT   = bfp + 991232;      // 720896   <- memset region end (bfp+1712128)
    bf16* adjb  = bfp + 1712128;     // 4194304
    bf16* adjtb = bfp + 5906432;     // 4194304
    bf16* adj2b = bfp + 10100736;    // 4194304
    bf16* yb    = bfp + 14295040;    // 262144
    bf16* Wpre  = bfp + 14557184;    // 9216
    bf16* Wrub  = bfp + 14566400;    // 45056
    bf16* Wcb   = bfp + 14611456;    // 22528

    float* imp  = (float*)d_out;
    float* pred = imp + (size_t)BB * NN * TT;
    float* repr = imp + (size_t)2 * BB * NN * TT;

    hipMemsetAsync(hTf, 0, 131072 * 4 + (size_t)1712128 * 2, stream);
    hipLaunchKernelGGL(k_prep, dim3(334), dim3(256), 0, stream,
                       Wgc, bgc, Wdin, bdin, Wlout, blout, Wfs, Wr, Wu, Wc,
                       Wcomb, bcomb, blout2, Wpre, Wrub, Wcb);
    hipLaunchKernelGGL(k_cvtT, dim3(16, 16, 4), dim3(256), 0, stream, adj, adjb, adjtb);
    hipLaunchKernelGGL(k_a2, dim3(16, 16, 4), dim3(256), 0, stream, adjb, adjtb, adj2b);

    hipLaunchKernelGGL(k_pre, dim3(128), dim3(64), 0, stream,
                       Wpre, zT, Wcomb, bcomb, bfs, x, mask, yb, x1b, pred, 0);

    for (int t = 0; t < TT; ++t) {
        const int ncombo = (t < TT - 1) ? 12 : 4;
        hipLaunchKernelGGL(k_difN, dim3(32, ncombo), dim3(256), 0, stream,
                           0, adjb, adj2b, yb, zb, zcb, gcT, zT, zcT);
        hipLaunchKernelGGL(k_stepB, dim3(512), dim3(256), 0, stream,
                           gcT, hTf, Wlout, blout2, pa, Wro, bro, x1b, mask,
                           imp, repr, zb, zcb, zT, zcT, t);
        if (t < TT - 1) {
            hipLaunchKernelGGL(k_dif2, dim3(64, 8), dim3(256), 0, stream,
                               adjb, adj2b, zb, zT, zcT);
            hipLaunchKernelGGL(k_gates, dim3(128), dim3(128), 0, stream,
                               Wrub, zT, br, bu, hTf, uT, zcb, zcT);
            hipLaunchKernelGGL(k_difN, dim3(32, 8), dim3(256), 0, stream,
                               1, adjb, adj2b, yb, zb, zcb, gcT, zT, zcT);
            hipLaunchKernelGGL(k_cellpre, dim3(128), dim3(128), 0, stream,
                               Wcb, zcT, bc, uT, hTf, zT, zb,
                               Wpre, Wcomb, bcomb, bfs, x, mask, yb, x1b, pred, t + 1);
        }
    }
}

// Round 10
// 704.975 us; speedup vs baseline: 9.0379x; 1.0854x over previous
//
#include <hip/hip_runtime.h>
#include <hip/hip_bf16.h>
#include <cstddef>

#define NN 1024
#define BB 2
#define TT 12
#define ZS 352   // zT/zcT row stride: [h(0..63), x2(64), m(65), pad, 4 slots @68: [hdiff(0..63), x2d(64), md(65), pad]]

typedef __attribute__((ext_vector_type(8))) short short8;
typedef __attribute__((ext_vector_type(4))) short short4v;
typedef __attribute__((ext_vector_type(4))) float f32x4;
typedef __hip_bfloat16 bf16;

__device__ __forceinline__ float sigmoidf_(float v) { return 1.0f / (1.0f + expf(-v)); }
__device__ __forceinline__ short bf16s(float f) { bf16 h = __float2bfloat16(f); return *reinterpret_cast<short*>(&h); }

// ---------------- one-time weight prep ----------------
__device__ __forceinline__ float mapcol(const float* src, int c) {
    if (c < 64) return src[2 + c];
    if (c == 64) return src[0];
    if (c == 65) return src[1];
    if (c < 68 || c >= 340) return 0.f;
    const int d = c - 68, bk = d / 68, off = d % 68;
    if (off < 64) return src[66 + bk * 66 + 2 + off];
    if (off == 64) return src[66 + bk * 66];
    if (off == 65) return src[66 + bk * 66 + 1];
    return 0.f;
}

__global__ __launch_bounds__(256) void k_prep(
    const float* __restrict__ Wgc, const float* __restrict__ bgc,
    const float* __restrict__ Wdin, const float* __restrict__ bdin,
    const float* __restrict__ Wlout, const float* __restrict__ blout,
    const float* __restrict__ Wfs,
    const float* __restrict__ Wr, const float* __restrict__ Wu, const float* __restrict__ Wc,
    float* __restrict__ Wcomb, float* __restrict__ bcomb, float* __restrict__ blout2,
    bf16* __restrict__ Wpre, bf16* __restrict__ Wrub, bf16* __restrict__ Wcb,
    bf16* __restrict__ Wlb)
{
    const int idx = blockIdx.x * 256 + threadIdx.x;
    if (idx < 8448) {
        const int o = idx / 66, k = idx % 66;
        const float* g = Wgc + (size_t)(o & 63) * 128 + (o >> 6) * 64;
        float a = 0.f;
#pragma unroll 8
        for (int c = 0; c < 64; ++c) a += g[c] * Wdin[c * 66 + k];
        Wcomb[idx] = a;
    } else if (idx < 8576) {
        const int o = idx - 8448;
        const float* g = Wgc + (size_t)(o & 63) * 128 + (o >> 6) * 64;
        float a = 0.f;
#pragma unroll 8
        for (int c = 0; c < 64; ++c) a += g[c] * bdin[c];
        bcomb[o] = a;
    } else if (idx < 8640) {
        const int oc = idx - 8576;
        float a = blout[oc];
#pragma unroll 8
        for (int j = 0; j < 64; ++j) a += Wlout[(size_t)oc * 128 + j] * bgc[j];
        blout2[oc] = a;
    } else if (idx < 17856) {
        const int j = idx - 8640, r = j >> 6, k = j & 63;
        float v = 0.f;
        if (r == 0) v = Wfs[k];
        else if (r <= 128) {
            const int o = r - 1;
            const float* g = Wgc + (size_t)(o & 63) * 128 + (o >> 6) * 64;
#pragma unroll 8
            for (int c = 0; c < 64; ++c) v += g[c] * Wdin[c * 66 + 2 + k];
        }
        Wpre[j] = __float2bfloat16(v);
    } else if (idx < 62912) {
        const int j = idx - 17856, r = j / 352, c = j % 352;
        const float* src = (r < 64) ? (Wr + (size_t)r * 330) : (Wu + (size_t)(r - 64) * 330);
        Wrub[j] = __float2bfloat16(mapcol(src, c));
    } else if (idx < 85440) {
        const int j = idx - 62912, r = j / 352, c = j % 352;
        Wcb[j] = __float2bfloat16(mapcol(Wc + (size_t)r * 330, c));
    } else if (idx < 93632) {
        const int j = idx - 85440;
        Wlb[j] = __float2bfloat16(Wlout[j]);
    }
}

// ---------------- adj fp32 -> bf16 (adjb) + transposed (adjtb) ----------------
__global__ __launch_bounds__(256) void k_cvtT(const float* __restrict__ adj,
                                              bf16* __restrict__ adjb, bf16* __restrict__ adjtb)
{
    const int sb = blockIdx.z;
    const int r0 = blockIdx.y * 64, c0 = blockIdx.x * 64;
    const float* A = adj + ((size_t)sb << 20);
    __shared__ short tile[64][72];
    const int tr = threadIdx.x >> 4, tc = (threadIdx.x & 15) * 4;
#pragma unroll
    for (int i = 0; i < 4; ++i) {
        const int r = tr + i * 16;
        float4 v = *reinterpret_cast<const float4*>(&A[(size_t)(r0 + r) * NN + c0 + tc]);
        short4v o = { bf16s(v.x), bf16s(v.y), bf16s(v.z), bf16s(v.w) };
        *reinterpret_cast<short4v*>(&adjb[((size_t)sb << 20) + (size_t)(r0 + r) * NN + c0 + tc]) = o;
        tile[r][tc + 0] = o.x; tile[r][tc + 1] = o.y; tile[r][tc + 2] = o.z; tile[r][tc + 3] = o.w;
    }
    __syncthreads();
#pragma unroll
    for (int i = 0; i < 4; ++i) {
        const int v = tr + i * 16;
        short4v o = { tile[tc + 0][v], tile[tc + 1][v], tile[tc + 2][v], tile[tc + 3][v] };
        *reinterpret_cast<short4v*>(&adjtb[((size_t)sb << 20) + (size_t)(c0 + v) * NN + r0 + tc]) = o;
    }
}

// ---------------- A^2: R8 config — 64w x 32v per wave, acc[4][2], grid (8,16,4) ----------------
__global__ __launch_bounds__(256) void k_a2(const bf16* __restrict__ adjb,
                                            const bf16* __restrict__ adjtb,
                                            bf16* __restrict__ adj2b)
{
    const int sb = blockIdx.z;
    const int wave = threadIdx.x >> 6, lane = threadIdx.x & 63;
    const int lr = lane & 15, lq = lane >> 4;
    const int v0 = blockIdx.x * 128 + wave * 32;
    const int w0 = blockIdx.y * 64;
    const bf16* AT = adjtb + ((size_t)sb << 20) + (size_t)(v0 + lr) * NN + lq * 8;
    const bf16* Ar = adjb + ((size_t)sb << 20) + (size_t)(w0 + lr) * NN + lq * 8;
    f32x4 acc[4][2];
#pragma unroll
    for (int m = 0; m < 4; ++m)
#pragma unroll
        for (int nb = 0; nb < 2; ++nb) acc[m][nb] = (f32x4){0.f, 0.f, 0.f, 0.f};
#pragma unroll 2
    for (int k0 = 0; k0 < NN; k0 += 32) {
        short8 bfr[2], af[4];
#pragma unroll
        for (int nb = 0; nb < 2; ++nb)
            bfr[nb] = *reinterpret_cast<const short8*>(AT + (size_t)nb * 16 * NN + k0);
#pragma unroll
        for (int m = 0; m < 4; ++m)
            af[m] = *reinterpret_cast<const short8*>(Ar + (size_t)m * 16 * NN + k0);
#pragma unroll
        for (int m = 0; m < 4; ++m)
#pragma unroll
            for (int nb = 0; nb < 2; ++nb)
                acc[m][nb] = __builtin_amdgcn_mfma_f32_16x16x32_bf16(af[m], bfr[nb], acc[m][nb], 0, 0, 0);
    }
    bf16* D = adj2b + ((size_t)sb << 20);
#pragma unroll
    for (int m = 0; m < 4; ++m)
#pragma unroll
        for (int nb = 0; nb < 2; ++nb)
#pragma unroll
            for (int q = 0; q < 4; ++q)
                D[(size_t)(w0 + m * 16 + lq * 4 + q) * NN + v0 + nb * 16 + lr] = __float2bfloat16(acc[m][nb][q]);
}

// ---------------- pre (standalone, t=0): MFMA [Wfs;Wcomb_h].h + epilogue ----------------
__global__ __launch_bounds__(64) void k_pre(
    const bf16* __restrict__ Wpre, const bf16* __restrict__ zT,
    const float* __restrict__ Wcomb, const float* __restrict__ bcomb,
    const float* __restrict__ bfsp,
    const float* __restrict__ x, const int* __restrict__ mask,
    bf16* __restrict__ yb, float* __restrict__ pred, int t)
{
    const int lane = threadIdx.x & 63, lr = lane & 15, lq = lane >> 4;
    const int p = blockIdx.x * 16 + lr;
    const bf16* B = zT + (size_t)p * ZS;
    f32x4 acc[9];
#pragma unroll
    for (int m = 0; m < 9; ++m) acc[m] = (f32x4){0.f, 0.f, 0.f, 0.f};
#pragma unroll
    for (int ks = 0; ks < 2; ++ks) {
        short8 bfr = *reinterpret_cast<const short8*>(B + ks * 32 + lq * 8);
#pragma unroll
        for (int m = 0; m < 9; ++m) {
            short8 af = *reinterpret_cast<const short8*>(Wpre + (size_t)(m * 16 + lr) * 64 + ks * 32 + lq * 8);
            acc[m] = __builtin_amdgcn_mfma_f32_16x16x32_bf16(af, bfr, acc[m], 0, 0, 0);
        }
    }
    const int b = p >> 10, n = p & (NN - 1);
    const size_t xi = (size_t)p * TT + t;
    const float xs1v = acc[0][0] + bfsp[0];
    const float xs1 = __shfl(xs1v, lr);
    const int mi = mask[xi];
    const float mf = (float)mi;
    const float x1 = mi ? x[xi] : xs1;
    if (lq == 0) pred[xi] = xs1;
#pragma unroll
    for (int m = 0; m < 9; ++m)
#pragma unroll
        for (int q = 0; q < 4; ++q) {
            const int o = m * 16 + lq * 4 + q - 1;
            if (o >= 0 && o < 128) {
                const float val = acc[m][q] + Wcomb[o * 66] * x1 + Wcomb[o * 66 + 1] * mf + bcomb[o];
                yb[(size_t)(b * 128 + o) * NN + n] = __float2bfloat16(val);
            }
        }
}

// ---------------- difA: fused y-diffusion(both s) + dec2 + xs2  |  h-diffusion blocks ----------------
// blockIdx.y < 2 : b = y. 32 nodes; gc both supports; dec2 MFMA; xs2 reduce; imp/x2 writes.
// blockIdx.y >= 2: i = y-2 -> (b,s,ord) h-diffusion into zT slots (as before).
__global__ __launch_bounds__(256) void k_difA(
    const bf16* __restrict__ adjb, const bf16* __restrict__ adj2b,
    const bf16* __restrict__ yb, const bf16* __restrict__ zbi,
    const bf16* __restrict__ Wlb, const float* __restrict__ blout2,
    const float* __restrict__ prelu_a, const float* __restrict__ Wro,
    const float* __restrict__ bro, const float* __restrict__ x,
    const int* __restrict__ mask, const float* __restrict__ hTf,
    float* __restrict__ imp, float* __restrict__ repr,
    bf16* __restrict__ zb, bf16* __restrict__ zcb,
    bf16* __restrict__ zT, bf16* __restrict__ zcT, int t)
{
    const int wave = threadIdx.x >> 6, lane = threadIdx.x & 63;
    const int lr = lane & 15, lq = lane >> 4;
    const int n0 = blockIdx.x * 32;

    __shared__ f32x4 red[3][2][2][4][64];   // 48 KB
    __shared__ short gh[32][136];           // [node][g 0..63 | h 64..127] bf16
    __shared__ float hf[32][68];
    __shared__ float lo_sm[32][68];

    if (blockIdx.y >= 2) {
        // ---------- h-diffusion block ----------
        const int i = blockIdx.y - 2;
        const int b = i & 1, s = (i >> 1) & 1, ord = i >> 2;
        const int sb = s * 2 + b;
        const bf16* M = (ord ? adj2b : adjb) + ((size_t)sb << 20);
        const bf16* A = M + (size_t)(n0 + lr) * NN + lq * 8;
        const bf16* Xp = zbi + ((size_t)(b * 66 + lr)) * NN + lq * 8;
        f32x4 acc[2][4];
#pragma unroll
        for (int nt = 0; nt < 2; ++nt)
#pragma unroll
            for (int m = 0; m < 4; ++m) acc[nt][m] = (f32x4){0.f, 0.f, 0.f, 0.f};
        const int vbeg = wave * 256;
#pragma unroll 2
        for (int it = 0; it < 8; ++it) {
            const int v0 = vbeg + it * 32;
            short8 bfr[2], af[4];
#pragma unroll
            for (int nt = 0; nt < 2; ++nt)
                bfr[nt] = *reinterpret_cast<const short8*>(A + (size_t)nt * 16 * NN + v0);
#pragma unroll
            for (int m = 0; m < 4; ++m)
                af[m] = *reinterpret_cast<const short8*>(Xp + (size_t)m * 16 * NN + v0);
#pragma unroll
            for (int nt = 0; nt < 2; ++nt)
#pragma unroll
                for (int m = 0; m < 4; ++m)
                    acc[nt][m] = __builtin_amdgcn_mfma_f32_16x16x32_bf16(af[m], bfr[nt], acc[nt][m], 0, 0, 0);
        }
        if (wave > 0) {
#pragma unroll
            for (int nt = 0; nt < 2; ++nt)
#pragma unroll
                for (int m = 0; m < 4; ++m) red[wave - 1][0][nt][m][lane] = acc[nt][m];
        }
        __syncthreads();
        if (wave == 0) {
#pragma unroll
            for (int nt = 0; nt < 2; ++nt) {
#pragma unroll
                for (int m = 0; m < 4; ++m)
                    acc[nt][m] += red[0][0][nt][m][lane] + red[1][0][nt][m][lane] + red[2][0][nt][m][lane];
                const int p = b * NN + n0 + nt * 16 + lr;
                bf16* dst = zT + (size_t)p * ZS + 68 + (s * 2 + ord) * 68;
#pragma unroll
                for (int m = 0; m < 4; ++m) {
                    short4v o = { bf16s(acc[nt][m][0]), bf16s(acc[nt][m][1]),
                                  bf16s(acc[nt][m][2]), bf16s(acc[nt][m][3]) };
                    *reinterpret_cast<short4v*>(dst + m * 16 + lq * 4) = o;
                }
            }
        }
        return;
    }

    // ---------- fused block ----------
    const int b = blockIdx.y;
    // phase 1: y-diffusion both supports
    f32x4 acc[2][2][4];   // [s][nt][m]
#pragma unroll
    for (int s = 0; s < 2; ++s)
#pragma unroll
        for (int nt = 0; nt < 2; ++nt)
#pragma unroll
            for (int m = 0; m < 4; ++m) acc[s][nt][m] = (f32x4){0.f, 0.f, 0.f, 0.f};
    {
        const int vbeg = wave * 256;
#pragma unroll 2
        for (int it = 0; it < 8; ++it) {
            const int v0 = vbeg + it * 32;
            short8 bfr[2][2], af[2][4];
#pragma unroll
            for (int s = 0; s < 2; ++s) {
                const bf16* M = adjb + ((size_t)(s * 2 + b) << 20);
#pragma unroll
                for (int nt = 0; nt < 2; ++nt)
                    bfr[s][nt] = *reinterpret_cast<const short8*>(M + (size_t)(n0 + nt * 16 + lr) * NN + v0 + lq * 8);
#pragma unroll
                for (int m = 0; m < 4; ++m)
                    af[s][m] = *reinterpret_cast<const short8*>(yb + (size_t)(b * 128 + s * 64 + m * 16 + lr) * NN + v0 + lq * 8);
            }
#pragma unroll
            for (int s = 0; s < 2; ++s)
#pragma unroll
                for (int nt = 0; nt < 2; ++nt)
#pragma unroll
                    for (int m = 0; m < 4; ++m)
                        acc[s][nt][m] = __builtin_amdgcn_mfma_f32_16x16x32_bf16(af[s][m], bfr[s][nt], acc[s][nt][m], 0, 0, 0);
        }
    }
    // phase 2a: stash partials; waves 1,2 stage h into LDS + write repr h-part
    if (wave > 0) {
#pragma unroll
        for (int s = 0; s < 2; ++s)
#pragma unroll
            for (int nt = 0; nt < 2; ++nt)
#pragma unroll
                for (int m = 0; m < 4; ++m) red[wave - 1][s][nt][m][lane] = acc[s][nt][m];
    }
    if (wave == 1 || wave == 2) {
        const int nb = (wave - 1) * 16;
        for (int i = lane; i < 1024; i += 64) {
            const int node = nb + (i >> 6), oc = i & 63;
            const float hv = hTf[(size_t)(b * NN + n0 + node) * 64 + oc];
            hf[node][oc] = hv;
            gh[node][64 + oc] = bf16s(hv);
            repr[(((size_t)b * 128 + 64 + oc) * NN + (n0 + node)) * TT + t] = hv;
        }
    }
    __syncthreads();
    // phase 2b: wave 0 reduces + sums supports -> gh g-cols
    if (wave == 0) {
#pragma unroll
        for (int nt = 0; nt < 2; ++nt) {
#pragma unroll
            for (int m = 0; m < 4; ++m) {
                f32x4 g = acc[0][nt][m] + acc[1][nt][m];
#pragma unroll
                for (int w = 0; w < 3; ++w) g += red[w][0][nt][m][lane] + red[w][1][nt][m][lane];
                const int node = nt * 16 + lr;
#pragma unroll
                for (int q = 0; q < 4; ++q) gh[node][m * 16 + lq * 4 + q] = bf16s(g[q]);
            }
        }
    }
    __syncthreads();
    // phase 3: dec2 MFMA — wave w = oc-tile w
    {
        f32x4 dacc[2];
#pragma unroll
        for (int nt = 0; nt < 2; ++nt) dacc[nt] = (f32x4){0.f, 0.f, 0.f, 0.f};
#pragma unroll
        for (int ks = 0; ks < 4; ++ks) {
            short8 af = *reinterpret_cast<const short8*>(Wlb + (size_t)(wave * 16 + lr) * 128 + ks * 32 + lq * 8);
#pragma unroll
            for (int nt = 0; nt < 2; ++nt) {
                short8 bfr = *reinterpret_cast<const short8*>(&gh[nt * 16 + lr][ks * 32 + lq * 8]);
                dacc[nt] = __builtin_amdgcn_mfma_f32_16x16x32_bf16(af, bfr, dacc[nt], 0, 0, 0);
            }
        }
        const float pa = prelu_a[0];
#pragma unroll
        for (int nt = 0; nt < 2; ++nt) {
            const int node = nt * 16 + lr;
#pragma unroll
            for (int q = 0; q < 4; ++q) {
                const int oc = wave * 16 + lq * 4 + q;
                float v = dacc[nt][q] + blout2[oc];
                v = (v >= 0.f) ? v : pa * v;
                repr[(((size_t)b * 128 + oc) * NN + (n0 + node)) * TT + t] = v;
                lo_sm[node][oc] = v;
            }
        }
    }
    __syncthreads();
    // phase 4: xs2 reduce (8 lanes/node), imp, x2, z staging writes
    {
        const int node = threadIdx.x >> 3, sub = threadIdx.x & 7;
        float s = 0.f;
#pragma unroll
        for (int j = sub * 8; j < sub * 8 + 8; ++j)
            s += Wro[j] * lo_sm[node][j] + Wro[64 + j] * hf[node][j];
        s += __shfl_xor(s, 1); s += __shfl_xor(s, 2); s += __shfl_xor(s, 4);
        if (sub == 0) {
            const float xs2 = s + bro[0];
            const int n = n0 + node;
            const int p = b * NN + n;
            const size_t xi = (size_t)p * TT + t;
            imp[xi] = xs2;
            const int mi = mask[xi];
            const float x2 = mi ? x[xi] : xs2;   // m?x1:xs2 == m?x:xs2
            const bf16 x2b = __float2bfloat16(x2);
            const bf16 mb = __float2bfloat16((float)mi);
            zb[((size_t)b * 66 + 64) * NN + n] = x2b;
            zb[((size_t)b * 66 + 65) * NN + n] = mb;
            zcb[((size_t)b * 66 + 64) * NN + n] = x2b;
            zcb[((size_t)b * 66 + 65) * NN + n] = mb;
            zT[(size_t)p * ZS + 64] = x2b; zT[(size_t)p * ZS + 65] = mb;
            zcT[(size_t)p * ZS + 64] = x2b; zcT[(size_t)p * ZS + 65] = mb;
        }
    }
}

// ---------------- difN1: rh diffusion (2 n-tiles/wave, split-K 4 waves) ----------------
__global__ __launch_bounds__(256) void k_difN(
    const bf16* __restrict__ adjb, const bf16* __restrict__ adj2b,
    const bf16* __restrict__ zcb, float* __restrict__ gcT_unused,
    bf16* __restrict__ zcT)
{
    const int i = blockIdx.y;
    const int b = i & 1, s = (i >> 1) & 1, ord = i >> 2;
    const int wave = threadIdx.x >> 6, lane = threadIdx.x & 63;
    const int lr = lane & 15, lq = lane >> 4;
    const int n0 = blockIdx.x * 32;
    const int sb = s * 2 + b;
    const bf16* M = (ord ? adj2b : adjb) + ((size_t)sb << 20);
    const bf16* A = M + (size_t)(n0 + lr) * NN + lq * 8;
    const bf16* Xp = zcb + ((size_t)(b * 66 + lr)) * NN + lq * 8;

    f32x4 acc[2][4];
#pragma unroll
    for (int nt = 0; nt < 2; ++nt)
#pragma unroll
        for (int m = 0; m < 4; ++m) acc[nt][m] = (f32x4){0.f, 0.f, 0.f, 0.f};
    const int vbeg = wave * 256;
#pragma unroll 2
    for (int it = 0; it < 8; ++it) {
        const int v0 = vbeg + it * 32;
        short8 bfr[2], af[4];
#pragma unroll
        for (int nt = 0; nt < 2; ++nt)
            bfr[nt] = *reinterpret_cast<const short8*>(A + (size_t)nt * 16 * NN + v0);
#pragma unroll
        for (int m = 0; m < 4; ++m)
            af[m] = *reinterpret_cast<const short8*>(Xp + (size_t)m * 16 * NN + v0);
#pragma unroll
        for (int nt = 0; nt < 2; ++nt)
#pragma unroll
            for (int m = 0; m < 4; ++m)
                acc[nt][m] = __builtin_amdgcn_mfma_f32_16x16x32_bf16(af[m], bfr[nt], acc[nt][m], 0, 0, 0);
    }
    __shared__ f32x4 red[3][2][4][64];
    if (wave > 0) {
#pragma unroll
        for (int nt = 0; nt < 2; ++nt)
#pragma unroll
            for (int m = 0; m < 4; ++m) red[wave - 1][nt][m][lane] = acc[nt][m];
    }
    __syncthreads();
    if (wave == 0) {
#pragma unroll
        for (int nt = 0; nt < 2; ++nt) {
#pragma unroll
            for (int m = 0; m < 4; ++m)
                acc[nt][m] += red[0][nt][m][lane] + red[1][nt][m][lane] + red[2][nt][m][lane];
            const int p = b * NN + n0 + nt * 16 + lr;
            bf16* dst = zcT + (size_t)p * ZS + 68 + (s * 2 + ord) * 68;
#pragma unroll
            for (int m = 0; m < 4; ++m) {
                short4v o = { bf16s(acc[nt][m][0]), bf16s(acc[nt][m][1]),
                              bf16s(acc[nt][m][2]), bf16s(acc[nt][m][3]) };
                *reinterpret_cast<short4v*>(dst + m * 16 + lq * 4) = o;
            }
        }
    }
}

// ---------------- dif2: diffuse x2,m (2 ch) -> both zT and zcT slots ----------------
__global__ __launch_bounds__(256) void k_dif2(
    const bf16* __restrict__ adjb, const bf16* __restrict__ adj2b,
    const bf16* __restrict__ zb, bf16* __restrict__ zT, bf16* __restrict__ zcT)
{
    const int i = blockIdx.y;
    const int b = i & 1, s = (i >> 1) & 1, ord = i >> 2;
    const int sb = s * 2 + b;
    const int wave = threadIdx.x >> 6, lane = threadIdx.x & 63;
    const int lr = lane & 15, lq = lane >> 4;
    const int n0 = blockIdx.x * 16;
    const bf16* M = (ord ? adj2b : adjb) + ((size_t)sb << 20);
    const bf16* A = M + (size_t)(n0 + lr) * NN + lq * 8;
    const bf16* Xp = zb + ((size_t)(b * 66 + 64) + lr) * NN + lq * 8;

    f32x4 acc = (f32x4){0.f, 0.f, 0.f, 0.f};
    const short8 zsh = {0, 0, 0, 0, 0, 0, 0, 0};
    const int vbeg = wave * 256;
#pragma unroll 4
    for (int i2 = 0; i2 < 8; ++i2) {
        const int v0 = vbeg + i2 * 32;
        short8 bfr = *reinterpret_cast<const short8*>(A + v0);
        short8 af = (lr < 2) ? *reinterpret_cast<const short8*>(Xp + v0) : zsh;
        acc = __builtin_amdgcn_mfma_f32_16x16x32_bf16(af, bfr, acc, 0, 0, 0);
    }
    __shared__ f32x4 red2[3][64];
    if (wave > 0) red2[wave - 1][lane] = acc;
    __syncthreads();
    if (wave == 0 && lq == 0) {
        acc += red2[0][lane] + red2[1][lane] + red2[2][lane];
        const int p = b * NN + n0 + lr;
        const size_t off = (size_t)p * ZS + 68 + (s * 2 + ord) * 68 + 64;
#pragma unroll
        for (int q = 0; q < 2; ++q) {
            const bf16 v = __float2bfloat16(acc[q]);
            zT[off + q] = v; zcT[off + q] = v;
        }
    }
}

// ---------------- gates: 2-wave m-split MFMA [Wr;Wu].zT + epilogue ----------------
__global__ __launch_bounds__(128) void k_gates(
    const bf16* __restrict__ Wrub, const bf16* __restrict__ zT,
    const float* __restrict__ br, const float* __restrict__ bu,
    const float* __restrict__ hTf,
    float* __restrict__ uT, bf16* __restrict__ zcb, bf16* __restrict__ zcT)
{
    const int wave = threadIdx.x >> 6, lane = threadIdx.x & 63;
    const int lr = lane & 15, lq = lane >> 4;
    const int p = blockIdx.x * 16 + lr;
    const bf16* B = zT + (size_t)p * ZS;
    const bf16* WA = Wrub + (size_t)wave * 64 * ZS;
    f32x4 acc[4];
#pragma unroll
    for (int m = 0; m < 4; ++m) acc[m] = (f32x4){0.f, 0.f, 0.f, 0.f};
#pragma unroll 2
    for (int ks = 0; ks < 11; ++ks) {
        short8 bfr = *reinterpret_cast<const short8*>(B + ks * 32 + lq * 8);
#pragma unroll
        for (int m = 0; m < 4; ++m) {
            short8 af = *reinterpret_cast<const short8*>(WA + (size_t)(m * 16 + lr) * ZS + ks * 32 + lq * 8);
            acc[m] = __builtin_amdgcn_mfma_f32_16x16x32_bf16(af, bfr, acc[m], 0, 0, 0);
        }
    }
    const int b = p >> 10, n = p & (NN - 1);
    if (wave == 0) {
#pragma unroll
        for (int m = 0; m < 4; ++m) {
            short4v rq;
#pragma unroll
            for (int q = 0; q < 4; ++q) {
                const int oc = m * 16 + lq * 4 + q;
                const float rv = sigmoidf_(acc[m][q] + br[oc]);
                const float rh = rv * hTf[(size_t)p * 64 + oc];
                rq[q] = bf16s(rh);
                zcb[((size_t)b * 66 + oc) * NN + n] = __float2bfloat16(rh);
            }
            *reinterpret_cast<short4v*>(&zcT[(size_t)p * ZS + m * 16 + lq * 4]) = rq;
        }
    } else {
#pragma unroll
        for (int m = 0; m < 4; ++m) {
            f32x4 uq;
#pragma unroll
            for (int q = 0; q < 4; ++q) {
                const int oc = m * 16 + lq * 4 + q;
                uq[q] = sigmoidf_(acc[m][q] + bu[oc]);
            }
            *reinterpret_cast<f32x4*>(&uT[(size_t)p * 64 + m * 16 + lq * 4]) = uq;
        }
    }
}

// ---------------- cellpre: 2-wave m-split cell + pre(t+1) via LDS transpose ----------------
__global__ __launch_bounds__(128) void k_cellpre(
    const bf16* __restrict__ Wcb, const bf16* __restrict__ zcT,
    const float* __restrict__ bc, const float* __restrict__ uT,
    float* __restrict__ hTf, bf16* __restrict__ zT, bf16* __restrict__ zb,
    const bf16* __restrict__ Wpre, const float* __restrict__ Wcomb,
    const float* __restrict__ bcomb, const float* __restrict__ bfsp,
    const float* __restrict__ x, const int* __restrict__ mask,
    bf16* __restrict__ yb, float* __restrict__ pred, int tn)
{
    const int wave = threadIdx.x >> 6, lane = threadIdx.x & 63;
    const int lr = lane & 15, lq = lane >> 4;
    const int p = blockIdx.x * 16 + lr;
    const int b = p >> 10, n = p & (NN - 1);
    __shared__ short hsm[16][72];
    __shared__ float xs1s[16];

    {
        const bf16* B = zcT + (size_t)p * ZS;
        f32x4 acc[2];
#pragma unroll
        for (int mm = 0; mm < 2; ++mm) acc[mm] = (f32x4){0.f, 0.f, 0.f, 0.f};
#pragma unroll 2
        for (int ks = 0; ks < 11; ++ks) {
            short8 bfr = *reinterpret_cast<const short8*>(B + ks * 32 + lq * 8);
#pragma unroll
            for (int mm = 0; mm < 2; ++mm) {
                const int m = wave * 2 + mm;
                short8 af = *reinterpret_cast<const short8*>(Wcb + (size_t)(m * 16 + lr) * ZS + ks * 32 + lq * 8);
                acc[mm] = __builtin_amdgcn_mfma_f32_16x16x32_bf16(af, bfr, acc[mm], 0, 0, 0);
            }
        }
#pragma unroll
        for (int mm = 0; mm < 2; ++mm) {
            const int m = wave * 2 + mm;
            f32x4 hq;
            short4v hb;
#pragma unroll
            for (int q = 0; q < 4; ++q) {
                const int oc = m * 16 + lq * 4 + q;
                const float cv = tanhf(acc[mm][q] + bc[oc]);
                const float uv = uT[(size_t)p * 64 + oc];
                const float ho = hTf[(size_t)p * 64 + oc];
                const float hn = uv * ho + (1.f - uv) * cv;
                hq[q] = hn;
                hb[q] = bf16s(hn);
                zb[((size_t)b * 66 + oc) * NN + n] = __float2bfloat16(hn);
            }
            *reinterpret_cast<f32x4*>(&hTf[(size_t)p * 64 + m * 16 + lq * 4]) = hq;
            *reinterpret_cast<short4v*>(&zT[(size_t)p * ZS + m * 16 + lq * 4]) = hb;
            *reinterpret_cast<short4v*>(&hsm[lr][m * 16 + lq * 4]) = hb;
        }
    }
    __syncthreads();

    {
        const int MB = wave ? 4 : 5;
        f32x4 acc[5];
#pragma unroll
        for (int m = 0; m < 5; ++m) acc[m] = (f32x4){0.f, 0.f, 0.f, 0.f};
#pragma unroll
        for (int ks = 0; ks < 2; ++ks) {
            short8 bfr = *reinterpret_cast<const short8*>(&hsm[lr][ks * 32 + lq * 8]);
#pragma unroll
            for (int m = 0; m < 5; ++m) {
                if (m < MB) {
                    const int mm = wave ? 5 + m : m;
                    short8 af = *reinterpret_cast<const short8*>(Wpre + (size_t)(mm * 16 + lr) * 64 + ks * 32 + lq * 8);
                    acc[m] = __builtin_amdgcn_mfma_f32_16x16x32_bf16(af, bfr, acc[m], 0, 0, 0);
                }
            }
        }
        if (wave == 0 && lq == 0) xs1s[lr] = acc[0][0] + bfsp[0];
        __syncthreads();
        const float xs1 = xs1s[lr];
        const size_t xi = (size_t)p * TT + tn;
        const int mi = mask[xi];
        const float mf = (float)mi;
        const float x1 = mi ? x[xi] : xs1;
        if (wave == 0 && lq == 0) pred[xi] = xs1;
#pragma unroll
        for (int m = 0; m < 5; ++m) {
            if (m < MB) {
                const int mm = wave ? 5 + m : m;
#pragma unroll
                for (int q = 0; q < 4; ++q) {
                    const int o = mm * 16 + lq * 4 + q - 1;
                    if (o >= 0 && o < 128) {
                        const float val = acc[m][q] + Wcomb[o * 66] * x1 + Wcomb[o * 66 + 1] * mf + bcomb[o];
                        yb[(size_t)(b * 128 + o) * NN + n] = __float2bfloat16(val);
                    }
                }
            }
        }
    }
}

extern "C" void kernel_launch(void* const* d_in, const int* in_sizes, int n_in,
                              void* d_out, int out_size, void* d_ws, size_t ws_size,
                              hipStream_t stream)
{
    const float* x     = (const float*)d_in[0];
    const int*   mask  = (const int*)  d_in[1];
    const float* adj   = (const float*)d_in[2];
    const float* Wr    = (const float*)d_in[3];
    const float* br    = (const float*)d_in[4];
    const float* Wu    = (const float*)d_in[5];
    const float* bu    = (const float*)d_in[6];
    const float* Wc    = (const float*)d_in[7];
    const float* bc    = (const float*)d_in[8];
    const float* Wfs   = (const float*)d_in[9];
    const float* bfs   = (const float*)d_in[10];
    const float* Wdin  = (const float*)d_in[11];
    const float* bdin  = (const float*)d_in[12];
    const float* Wgc   = (const float*)d_in[13];
    const float* bgc   = (const float*)d_in[14];
    const float* Wlout = (const float*)d_in[15];
    const float* blout = (const float*)d_in[16];
    const float* Wro   = (const float*)d_in[17];
    const float* bro   = (const float*)d_in[18];
    const float* pa    = (const float*)d_in[19];

    float* ws = (float*)d_ws;
    float* Wcomb  = ws + 0;          // 8448
    float* bcomb  = ws + 8448;       // 128
    float* blout2 = ws + 8576;       // 64
    float* uT     = ws + 272832;     // 131072
    float* hTf    = ws + 403904;     // 131072   <- memset region start
    bf16* bfp   = (bf16*)(ws + 534976);
    bf16* zb    = bfp + 0;           // 135168
    bf16* zcb   = bfp + 135168;      // 135168
    bf16* zT    = bfp + 270336;      // 720896
    bf16* zcT   = bfp + 991232;      // 720896   <- memset region end (bfp+1712128)
    bf16* adjb  = bfp + 1712128;     // 4194304
    bf16* adjtb = bfp + 5906432;     // 4194304
    bf16* adj2b = bfp + 10100736;    // 4194304
    bf16* yb    = bfp + 14295040;    // 262144
    bf16* Wpre  = bfp + 14557184;    // 9216
    bf16* Wrub  = bfp + 14566400;    // 45056
    bf16* Wcb   = bfp + 14611456;    // 22528
    bf16* Wlb   = bfp + 14633984;    // 8192

    float* imp  = (float*)d_out;
    float* pred = imp + (size_t)BB * NN * TT;
    float* repr = imp + (size_t)2 * BB * NN * TT;

    hipMemsetAsync(hTf, 0, 131072 * 4 + (size_t)1712128 * 2, stream);
    hipLaunchKernelGGL(k_prep, dim3(366), dim3(256), 0, stream,
                       Wgc, bgc, Wdin, bdin, Wlout, blout, Wfs, Wr, Wu, Wc,
                       Wcomb, bcomb, blout2, Wpre, Wrub, Wcb, Wlb);
    hipLaunchKernelGGL(k_cvtT, dim3(16, 16, 4), dim3(256), 0, stream, adj, adjb, adjtb);
    hipLaunchKernelGGL(k_a2, dim3(8, 16, 4), dim3(256), 0, stream, adjb, adjtb, adj2b);

    hipLaunchKernelGGL(k_pre, dim3(128), dim3(64), 0, stream,
                       Wpre, zT, Wcomb, bcomb, bfs, x, mask, yb, pred, 0);

    for (int t = 0; t < TT; ++t) {
        const int ny = (t < TT - 1) ? 10 : 2;
        hipLaunchKernelGGL(k_difA, dim3(32, ny), dim3(256), 0, stream,
                           adjb, adj2b, yb, zb, Wlb, blout2, pa, Wro, bro, x, mask,
                           hTf, imp, repr, zb, zcb, zT, zcT, t);
        if (t < TT - 1) {
            hipLaunchKernelGGL(k_dif2, dim3(64, 8), dim3(256), 0, stream,
                               adjb, adj2b, zb, zT, zcT);
            hipLaunchKernelGGL(k_gates, dim3(128), dim3(128), 0, stream,
                               Wrub, zT, br, bu, hTf, uT, zcb, zcT);
            hipLaunchKernelGGL(k_difN, dim3(32, 8), dim3(256), 0, stream,
                               adjb, adj2b, zcb, (float*)nullptr, zcT);
            hipLaunchKernelGGL(k_cellpre, dim3(128), dim3(128), 0, stream,
                               Wcb, zcT, bc, uT, hTf, zT, zb,
                               Wpre, Wcomb, bcomb, bfs, x, mask, yb, pred, t + 1);
        }
    }
}